// Round 1
// baseline (1075.914 us; speedup 1.0000x reference)
//
#include <hip/hip_runtime.h>
#include <math.h>

// Problem constants
#define BATCH 4
#define LSEQ  1024
#define DIM   256
#define ESZ   512      // E = 2*DIM
#define NST   32       // D_STATE
#define RNK   16       // DT_RANK
#define MROWS 4096     // B*L

// ---------------------------------------------------------------------------
// LayerNorm over last dim (=256). One block (256 thr) per row.
// ---------------------------------------------------------------------------
__global__ __launch_bounds__(256) void ln_kernel(
    const float* __restrict__ x, const float* __restrict__ g,
    const float* __restrict__ b, float* __restrict__ y)
{
    const int row = blockIdx.x;
    const int tid = threadIdx.x;
    float v = x[row * DIM + tid];
    float s = v, s2 = v * v;
    #pragma unroll
    for (int o = 32; o > 0; o >>= 1) {
        s  += __shfl_down(s,  o, 64);
        s2 += __shfl_down(s2, o, 64);
    }
    __shared__ float ls[4], ls2[4];
    if ((tid & 63) == 0) { ls[tid >> 6] = s; ls2[tid >> 6] = s2; }
    __syncthreads();
    float ts  = ls[0]  + ls[1]  + ls[2]  + ls[3];
    float ts2 = ls2[0] + ls2[1] + ls2[2] + ls2[3];
    float mean = ts * (1.f / DIM);
    float var  = ts2 * (1.f / DIM) - mean * mean;
    float inv  = rsqrtf(var + 1e-5f);
    y[row * DIM + tid] = (v - mean) * inv * g[tid] + b[tid];
}

// ---------------------------------------------------------------------------
// dwconv window-3 pad(1,1) + bias + residual add:  hm = conv3(h1)+cb + h1
// ---------------------------------------------------------------------------
__global__ __launch_bounds__(256) void conv3_add_kernel(
    const float* __restrict__ h1, const float* __restrict__ w,
    const float* __restrict__ cb, float* __restrict__ hm)
{
    const int i  = blockIdx.x * 256 + threadIdx.x;   // over 4096*256
    const int d  = i & (DIM - 1);
    const int bl = i >> 8;
    const int l  = bl & (LSEQ - 1);
    float c   = h1[i];
    float acc = w[d * 3 + 1] * c + cb[d] + c;
    if (l > 0)        acc += w[d * 3 + 0] * h1[i - DIM];
    if (l < LSEQ - 1) acc += w[d * 3 + 2] * h1[i + DIM];
    hm[i] = acc;
}

// ---------------------------------------------------------------------------
// causal dwconv window-4 pad(3,0) + bias + SiLU.  xin = xz[:, :512]
// ---------------------------------------------------------------------------
__global__ __launch_bounds__(256) void conv4_silu_kernel(
    const float* __restrict__ xz, const float* __restrict__ w,
    const float* __restrict__ cb, float* __restrict__ u)
{
    const int i  = blockIdx.x * 256 + threadIdx.x;   // over 4096*512
    const int e  = i & (ESZ - 1);
    const int bl = i >> 9;
    const int l  = bl & (LSEQ - 1);
    float acc = cb[e];
    #pragma unroll
    for (int k = 0; k < 4; ++k) {
        int ls = l + k - 3;
        if (ls >= 0) acc += w[e * 4 + k] * xz[(long)(bl + k - 3) * 1024 + e];
    }
    float sv = acc / (1.f + __expf(-acc));
    u[(long)bl * ESZ + e] = sv;
}

// ---------------------------------------------------------------------------
// Generic fp32 GEMM: C[M,N] = A[M,K] @ W[N,K]^T  (+ epilogue)
// 64x64 tile, BK=16, 256 threads, 4x4 micro-tile.
// ---------------------------------------------------------------------------
#define EPI_NONE      0
#define EPI_SOFTPLUS  1
#define EPI_GELU      2
#define EPI_RES       3
#define EPI_BIAS_RES  4

template <int EPI>
__global__ __launch_bounds__(256) void gemm_nt(
    const float* __restrict__ A, int lda,
    const float* __restrict__ W, int ldw,
    float* __restrict__ C, int ldc,
    int M, int N, int K,
    const float* __restrict__ bias,
    const float* __restrict__ res, int ldres)
{
    __shared__ float As[16][68];
    __shared__ float Bs[16][68];
    const int tid = threadIdx.x;
    const int m0 = blockIdx.x * 64;
    const int n0 = blockIdx.y * 64;
    const int tx = tid & 15, ty = tid >> 4;
    const int lr = tid >> 2;           // 0..63 row in tile
    const int lk = (tid & 3) << 2;     // 0,4,8,12

    const float* Ap = A + (m0 + lr) * lda + lk;
    const float* Wp = W + (n0 + lr) * ldw + lk;
    const bool wv = (n0 + lr) < N;

    float acc[4][4];
    #pragma unroll
    for (int i = 0; i < 4; ++i)
        #pragma unroll
        for (int j = 0; j < 4; ++j) acc[i][j] = 0.f;

    for (int k0 = 0; k0 < K; k0 += 16) {
        float4 av = *(const float4*)(Ap + k0);
        float4 wvv = wv ? *(const float4*)(Wp + k0) : make_float4(0.f, 0.f, 0.f, 0.f);
        __syncthreads();
        As[lk + 0][lr] = av.x;  As[lk + 1][lr] = av.y;
        As[lk + 2][lr] = av.z;  As[lk + 3][lr] = av.w;
        Bs[lk + 0][lr] = wvv.x; Bs[lk + 1][lr] = wvv.y;
        Bs[lk + 2][lr] = wvv.z; Bs[lk + 3][lr] = wvv.w;
        __syncthreads();
        #pragma unroll
        for (int k = 0; k < 16; ++k) {
            float a0 = As[k][ty * 4 + 0], a1 = As[k][ty * 4 + 1];
            float a2 = As[k][ty * 4 + 2], a3 = As[k][ty * 4 + 3];
            float b0 = Bs[k][tx * 4 + 0], b1 = Bs[k][tx * 4 + 1];
            float b2 = Bs[k][tx * 4 + 2], b3 = Bs[k][tx * 4 + 3];
            acc[0][0] += a0 * b0; acc[0][1] += a0 * b1; acc[0][2] += a0 * b2; acc[0][3] += a0 * b3;
            acc[1][0] += a1 * b0; acc[1][1] += a1 * b1; acc[1][2] += a1 * b2; acc[1][3] += a1 * b3;
            acc[2][0] += a2 * b0; acc[2][1] += a2 * b1; acc[2][2] += a2 * b2; acc[2][3] += a2 * b3;
            acc[3][0] += a3 * b0; acc[3][1] += a3 * b1; acc[3][2] += a3 * b2; acc[3][3] += a3 * b3;
        }
    }

    #pragma unroll
    for (int i = 0; i < 4; ++i) {
        const int mm = m0 + ty * 4 + i;
        float* crow = C + (long)mm * ldc;
        const float* rrow = (EPI == EPI_RES || EPI == EPI_BIAS_RES)
                              ? res + (long)mm * ldres : nullptr;
        float v4[4];
        #pragma unroll
        for (int j = 0; j < 4; ++j) {
            const int nn = n0 + tx * 4 + j;
            float v = acc[i][j];
            if (EPI == EPI_SOFTPLUS) {
                v += bias[(nn < N) ? nn : 0];
                v = (v > 20.f) ? v : log1pf(__expf(v));
            } else if (EPI == EPI_GELU) {
                v += bias[(nn < N) ? nn : 0];
                v = 0.5f * v * (1.f + erff(v * 0.70710678118654752f));
            } else if (EPI == EPI_RES) {
                v += (nn < N) ? rrow[nn] : 0.f;
            } else if (EPI == EPI_BIAS_RES) {
                v += ((nn < N) ? bias[nn] : 0.f) + ((nn < N) ? rrow[nn] : 0.f);
            }
            v4[j] = v;
        }
        const int nbase = n0 + tx * 4;
        if (nbase + 3 < N) {
            float4 o4 = make_float4(v4[0], v4[1], v4[2], v4[3]);
            *(float4*)(crow + nbase) = o4;
        } else {
            #pragma unroll
            for (int j = 0; j < 4; ++j)
                if (nbase + j < N) crow[nbase + j] = v4[j];
        }
    }
}

// ---------------------------------------------------------------------------
// Selective scan. Block = 256 thr = 8 channels (32 state-lanes each).
// Grid = B * E/8 = 256. Fused: y = sum_n h*C + u*D, then y *= silu(z).
// ---------------------------------------------------------------------------
__global__ __launch_bounds__(256) void scan_kernel(
    const float* __restrict__ dt, const float* __restrict__ u,
    const float* __restrict__ dbl, const float* __restrict__ A_log,
    const float* __restrict__ Dp, const float* __restrict__ xz,
    float* __restrict__ yg)
{
    const int tid = threadIdx.x;
    const int n  = tid & 31;
    const int ch = tid >> 5;                    // 0..7
    const int b  = blockIdx.x >> 6;             // 64 e-tiles per batch
    const int e  = ((blockIdx.x & 63) << 3) + ch;

    const float Aen = -__expf(A_log[e * NST + n]);
    const float dpe = Dp[e];
    float h = 0.f;
    const long base = (long)b * LSEQ;

    for (int l = 0; l < LSEQ; ++l) {
        const long bl = base + l;
        float ldt = dt[bl * ESZ + e];
        float lu  = u[bl * ESZ + e];
        float bn  = dbl[bl * 80 + 16 + n];
        float cn  = dbl[bl * 80 + 48 + n];
        float dA  = __expf(ldt * Aen);
        h = dA * h + ldt * bn * lu;
        float p = h * cn;
        #pragma unroll
        for (int o = 16; o > 0; o >>= 1) p += __shfl_xor(p, o, 32);
        if (n == 0) {
            float y = p + lu * dpe;
            float z = xz[bl * 1024 + ESZ + e];
            yg[bl * ESZ + e] = y * (z / (1.f + __expf(-z)));
        }
    }
}

// ---------------------------------------------------------------------------
extern "C" void kernel_launch(void* const* d_in, const int* in_sizes, int n_in,
                              void* d_out, int out_size, void* d_ws, size_t ws_size,
                              hipStream_t stream)
{
    const float* x    = (const float*)d_in[0];
    const float* n1g  = (const float*)d_in[1];
    const float* n1b  = (const float*)d_in[2];
    const float* cw   = (const float*)d_in[3];
    const float* cb   = (const float*)d_in[4];
    const float* ipw  = (const float*)d_in[5];
    const float* scw  = (const float*)d_in[6];
    const float* scb  = (const float*)d_in[7];
    const float* xpw  = (const float*)d_in[8];
    const float* dtw  = (const float*)d_in[9];
    const float* dtb  = (const float*)d_in[10];
    const float* alog = (const float*)d_in[11];
    const float* dp   = (const float*)d_in[12];
    const float* opw  = (const float*)d_in[13];
    const float* n2g  = (const float*)d_in[14];
    const float* n2b  = (const float*)d_in[15];
    const float* w1   = (const float*)d_in[16];
    const float* b1   = (const float*)d_in[17];
    const float* w2   = (const float*)d_in[18];
    const float* b2   = (const float*)d_in[19];
    float* out = (float*)d_out;

    // Workspace layout (floats)
    float* ws   = (float*)d_ws;
    float* h1   = ws;                    // 4096*256  (reused for LN2 output)
    float* hm   = h1 + 1048576;          // 4096*256
    float* xz   = hm + 1048576;          // 4096*1024 (reused as MLP mid)
    float* u    = xz + 4194304;          // 4096*512
    float* dbl  = u + 2097152;           // 4096*80
    float* dt   = dbl + 327680;          // 4096*512
    float* yg   = dt + 2097152;          // 4096*512
    float* hres = yg + 2097152;          // 4096*256
    float* mid  = xz;                    // alias: xz dead after scan

    // 1. LN1
    ln_kernel<<<MROWS, 256, 0, stream>>>(x, n1g, n1b, h1);
    // 2. conv3 + add
    conv3_add_kernel<<<MROWS, 256, 0, stream>>>(h1, cw, cb, hm);
    // 3. in_proj: xz = hm @ ipw^T  [4096,1024,256]
    gemm_nt<EPI_NONE><<<dim3(64, 16), 256, 0, stream>>>(
        hm, 256, ipw, 256, xz, 1024, MROWS, 1024, 256, nullptr, nullptr, 0);
    // 4. causal conv4 + silu
    conv4_silu_kernel<<<8192, 256, 0, stream>>>(xz, scw, scb, u);
    // 5. x_proj: dbl = u @ xpw^T  [4096,80,512]
    gemm_nt<EPI_NONE><<<dim3(64, 2), 256, 0, stream>>>(
        u, 512, xpw, 512, dbl, 80, MROWS, 80, 512, nullptr, nullptr, 0);
    // 6. dt_proj + softplus: dt = softplus(dbl[:, :16] @ dtw^T + dtb)
    gemm_nt<EPI_SOFTPLUS><<<dim3(64, 8), 256, 0, stream>>>(
        dbl, 80, dtw, 16, dt, 512, MROWS, 512, 16, dtb, nullptr, 0);
    // 7. selective scan + gating
    scan_kernel<<<256, 256, 0, stream>>>(dt, u, dbl, alog, dp, xz, yg);
    // 8. out_proj + residual: hres = yg @ opw^T + x
    gemm_nt<EPI_RES><<<dim3(64, 4), 256, 0, stream>>>(
        yg, 512, opw, 512, hres, 256, MROWS, 256, 512, nullptr, x, 256);
    // 9. LN2
    ln_kernel<<<MROWS, 256, 0, stream>>>(hres, n2g, n2b, h1);
    // 10. MLP1 + gelu: mid = gelu(h1 @ w1^T + b1)
    gemm_nt<EPI_GELU><<<dim3(64, 16), 256, 0, stream>>>(
        h1, 256, w1, 256, mid, 1024, MROWS, 1024, 256, b1, nullptr, 0);
    // 11. MLP2 + bias + residual: out = mid @ w2^T + b2 + hres
    gemm_nt<EPI_BIAS_RES><<<dim3(64, 4), 256, 0, stream>>>(
        mid, 1024, w2, 1024, out, 256, MROWS, 256, 1024, b2, hres, 256);
}

// Round 2
// 452.796 us; speedup vs baseline: 2.3762x; 2.3762x over previous
//
#include <hip/hip_runtime.h>
#include <math.h>

// Problem constants
#define BATCH 4
#define LSEQ  1024
#define DIM   256
#define ESZ   512      // E = 2*DIM
#define NST   32       // D_STATE
#define RNK   16       // DT_RANK
#define MROWS 4096     // B*L
#define NCH   16       // scan chunks
#define CHL   64       // chunk length (NCH*CHL == LSEQ)

// ---------------------------------------------------------------------------
// LayerNorm over last dim (=256). One block (256 thr) per row.
// ---------------------------------------------------------------------------
__global__ __launch_bounds__(256) void ln_kernel(
    const float* __restrict__ x, const float* __restrict__ g,
    const float* __restrict__ b, float* __restrict__ y)
{
    const int row = blockIdx.x;
    const int tid = threadIdx.x;
    float v = x[row * DIM + tid];
    float s = v, s2 = v * v;
    #pragma unroll
    for (int o = 32; o > 0; o >>= 1) {
        s  += __shfl_down(s,  o, 64);
        s2 += __shfl_down(s2, o, 64);
    }
    __shared__ float ls[4], ls2[4];
    if ((tid & 63) == 0) { ls[tid >> 6] = s; ls2[tid >> 6] = s2; }
    __syncthreads();
    float ts  = ls[0]  + ls[1]  + ls[2]  + ls[3];
    float ts2 = ls2[0] + ls2[1] + ls2[2] + ls2[3];
    float mean = ts * (1.f / DIM);
    float var  = ts2 * (1.f / DIM) - mean * mean;
    float inv  = rsqrtf(var + 1e-5f);
    y[row * DIM + tid] = (v - mean) * inv * g[tid] + b[tid];
}

// ---------------------------------------------------------------------------
// dwconv window-3 pad(1,1) + bias + residual add:  hm = conv3(h1)+cb + h1
// ---------------------------------------------------------------------------
__global__ __launch_bounds__(256) void conv3_add_kernel(
    const float* __restrict__ h1, const float* __restrict__ w,
    const float* __restrict__ cb, float* __restrict__ hm)
{
    const int i  = blockIdx.x * 256 + threadIdx.x;   // over 4096*256
    const int d  = i & (DIM - 1);
    const int bl = i >> 8;
    const int l  = bl & (LSEQ - 1);
    float c   = h1[i];
    float acc = w[d * 3 + 1] * c + cb[d] + c;
    if (l > 0)        acc += w[d * 3 + 0] * h1[i - DIM];
    if (l < LSEQ - 1) acc += w[d * 3 + 2] * h1[i + DIM];
    hm[i] = acc;
}

// ---------------------------------------------------------------------------
// causal dwconv window-4 pad(3,0) + bias + SiLU.  xin = xz[:, :512]
// ---------------------------------------------------------------------------
__global__ __launch_bounds__(256) void conv4_silu_kernel(
    const float* __restrict__ xz, const float* __restrict__ w,
    const float* __restrict__ cb, float* __restrict__ u)
{
    const int i  = blockIdx.x * 256 + threadIdx.x;   // over 4096*512
    const int e  = i & (ESZ - 1);
    const int bl = i >> 9;
    const int l  = bl & (LSEQ - 1);
    float acc = cb[e];
    #pragma unroll
    for (int k = 0; k < 4; ++k) {
        int ls = l + k - 3;
        if (ls >= 0) acc += w[e * 4 + k] * xz[(long)(bl + k - 3) * 1024 + e];
    }
    float sv = acc / (1.f + __expf(-acc));
    u[(long)bl * ESZ + e] = sv;
}

// ---------------------------------------------------------------------------
// Generic fp32 GEMM: C[M,N] = A[M,K] @ W[N,K]^T  (+ epilogue)
// 64x64 tile, BK=16, 256 threads, 4x4 micro-tile.
// ---------------------------------------------------------------------------
#define EPI_NONE      0
#define EPI_SOFTPLUS  1
#define EPI_GELU      2
#define EPI_RES       3
#define EPI_BIAS_RES  4

template <int EPI>
__global__ __launch_bounds__(256) void gemm_nt(
    const float* __restrict__ A, int lda,
    const float* __restrict__ W, int ldw,
    float* __restrict__ C, int ldc,
    int M, int N, int K,
    const float* __restrict__ bias,
    const float* __restrict__ res, int ldres)
{
    __shared__ float As[16][68];
    __shared__ float Bs[16][68];
    const int tid = threadIdx.x;
    const int m0 = blockIdx.x * 64;
    const int n0 = blockIdx.y * 64;
    const int tx = tid & 15, ty = tid >> 4;
    const int lr = tid >> 2;           // 0..63 row in tile
    const int lk = (tid & 3) << 2;     // 0,4,8,12

    const float* Ap = A + (m0 + lr) * lda + lk;
    const float* Wp = W + (n0 + lr) * ldw + lk;
    const bool wv = (n0 + lr) < N;

    float acc[4][4];
    #pragma unroll
    for (int i = 0; i < 4; ++i)
        #pragma unroll
        for (int j = 0; j < 4; ++j) acc[i][j] = 0.f;

    for (int k0 = 0; k0 < K; k0 += 16) {
        float4 av = *(const float4*)(Ap + k0);
        float4 wvv = wv ? *(const float4*)(Wp + k0) : make_float4(0.f, 0.f, 0.f, 0.f);
        __syncthreads();
        As[lk + 0][lr] = av.x;  As[lk + 1][lr] = av.y;
        As[lk + 2][lr] = av.z;  As[lk + 3][lr] = av.w;
        Bs[lk + 0][lr] = wvv.x; Bs[lk + 1][lr] = wvv.y;
        Bs[lk + 2][lr] = wvv.z; Bs[lk + 3][lr] = wvv.w;
        __syncthreads();
        #pragma unroll
        for (int k = 0; k < 16; ++k) {
            float a0 = As[k][ty * 4 + 0], a1 = As[k][ty * 4 + 1];
            float a2 = As[k][ty * 4 + 2], a3 = As[k][ty * 4 + 3];
            float b0 = Bs[k][tx * 4 + 0], b1 = Bs[k][tx * 4 + 1];
            float b2 = Bs[k][tx * 4 + 2], b3 = Bs[k][tx * 4 + 3];
            acc[0][0] += a0 * b0; acc[0][1] += a0 * b1; acc[0][2] += a0 * b2; acc[0][3] += a0 * b3;
            acc[1][0] += a1 * b0; acc[1][1] += a1 * b1; acc[1][2] += a1 * b2; acc[1][3] += a1 * b3;
            acc[2][0] += a2 * b0; acc[2][1] += a2 * b1; acc[2][2] += a2 * b2; acc[2][3] += a2 * b3;
            acc[3][0] += a3 * b0; acc[3][1] += a3 * b1; acc[3][2] += a3 * b2; acc[3][3] += a3 * b3;
        }
    }

    #pragma unroll
    for (int i = 0; i < 4; ++i) {
        const int mm = m0 + ty * 4 + i;
        float* crow = C + (long)mm * ldc;
        const float* rrow = (EPI == EPI_RES || EPI == EPI_BIAS_RES)
                              ? res + (long)mm * ldres : nullptr;
        float v4[4];
        #pragma unroll
        for (int j = 0; j < 4; ++j) {
            const int nn = n0 + tx * 4 + j;
            float v = acc[i][j];
            if (EPI == EPI_SOFTPLUS) {
                v += bias[(nn < N) ? nn : 0];
                v = (v > 20.f) ? v : log1pf(__expf(v));
            } else if (EPI == EPI_GELU) {
                v += bias[(nn < N) ? nn : 0];
                v = 0.5f * v * (1.f + erff(v * 0.70710678118654752f));
            } else if (EPI == EPI_RES) {
                v += (nn < N) ? rrow[nn] : 0.f;
            } else if (EPI == EPI_BIAS_RES) {
                v += ((nn < N) ? bias[nn] : 0.f) + ((nn < N) ? rrow[nn] : 0.f);
            }
            v4[j] = v;
        }
        const int nbase = n0 + tx * 4;
        if (nbase + 3 < N) {
            float4 o4 = make_float4(v4[0], v4[1], v4[2], v4[3]);
            *(float4*)(crow + nbase) = o4;
        } else {
            #pragma unroll
            for (int j = 0; j < 4; ++j)
                if (nbase + j < N) crow[nbase + j] = v4[j];
        }
    }
}

// ---------------------------------------------------------------------------
// Chunked parallel selective scan.
// h_t = dA_t * h_{t-1} + dt_t*B_t*u_t  is a linear recurrence; decompose
// L=1024 into NCH=16 chunks of CHL=64.
// S1: per (b,e,chunk,n) compute (P=prod dA, Q=chunk-local scan from 0).
// S2: per (b,e,n) sequential scan over the 16 chunk summaries -> Hinit.
// S3: per (b,e,chunk) recompute from Hinit, reduce y over n lanes, gate.
// Group mapping (S1/S3): gid = ((b*512+e)*16 + c), lanes = n (32).
// ---------------------------------------------------------------------------
__global__ __launch_bounds__(256) void scan_s1(
    const float* __restrict__ dt, const float* __restrict__ u,
    const float* __restrict__ dbl, const float* __restrict__ A_log,
    float* __restrict__ P, float* __restrict__ Q)
{
    const int tid = threadIdx.x;
    const int n   = tid & 31;
    const int gid = blockIdx.x * 8 + (tid >> 5);
    const int c   = gid & (NCH - 1);
    const int e   = (gid >> 4) & (ESZ - 1);
    const int b   = gid >> 13;
    const float Aen = -__expf(A_log[e * NST + n]);
    float Pv = 1.f, Qv = 0.f;
    const int base = b * LSEQ + c * CHL;
    #pragma unroll 4
    for (int t = 0; t < CHL; ++t) {
        const long bl = base + t;
        float ldt = dt[bl * ESZ + e];     // broadcast across lanes
        float lu  = u[bl * ESZ + e];      // broadcast
        float bn  = dbl[bl * 80 + 16 + n];
        float dA  = __expf(ldt * Aen);
        Pv *= dA;
        Qv = dA * Qv + ldt * bn * lu;
    }
    P[(long)gid * NST + n] = Pv;
    Q[(long)gid * NST + n] = Qv;
}

// In-place: writes Hinit (chunk-entry state) over P.
__global__ __launch_bounds__(256) void scan_s2(
    float* __restrict__ P, const float* __restrict__ Q)
{
    const int t  = blockIdx.x * 256 + threadIdx.x;  // (b,e,n) over 65536
    const int n  = t & 31;
    const int be = t >> 5;                          // b*512+e
    float h = 0.f;
    #pragma unroll
    for (int c = 0; c < NCH; ++c) {
        const int idx = be * (NCH * NST) + c * NST + n;
        float Pv = P[idx];
        float Qv = Q[idx];
        P[idx] = h;            // Hinit for chunk c
        h = Pv * h + Qv;
    }
}

__global__ __launch_bounds__(256) void scan_s3(
    const float* __restrict__ dt, const float* __restrict__ u,
    const float* __restrict__ dbl, const float* __restrict__ A_log,
    const float* __restrict__ Dp, const float* __restrict__ xz,
    const float* __restrict__ H, float* __restrict__ yg)
{
    const int tid = threadIdx.x;
    const int n   = tid & 31;
    const int gid = blockIdx.x * 8 + (tid >> 5);
    const int c   = gid & (NCH - 1);
    const int e   = (gid >> 4) & (ESZ - 1);
    const int b   = gid >> 13;
    const float Aen = -__expf(A_log[e * NST + n]);
    const float dpe = Dp[e];
    float h = H[(long)gid * NST + n];
    const int base = b * LSEQ + c * CHL;
    #pragma unroll 2
    for (int t = 0; t < CHL; ++t) {
        const long bl = base + t;
        float ldt = dt[bl * ESZ + e];
        float lu  = u[bl * ESZ + e];
        float bn  = dbl[bl * 80 + 16 + n];
        float cn  = dbl[bl * 80 + 48 + n];
        float dA  = __expf(ldt * Aen);
        h = dA * h + ldt * bn * lu;
        float p = h * cn;
        #pragma unroll
        for (int o = 16; o > 0; o >>= 1) p += __shfl_xor(p, o, 32);
        if (n == 0) {
            float y = p + lu * dpe;
            float z = xz[bl * 1024 + ESZ + e];
            yg[bl * ESZ + e] = y * (z / (1.f + __expf(-z)));
        }
    }
}

// ---------------------------------------------------------------------------
extern "C" void kernel_launch(void* const* d_in, const int* in_sizes, int n_in,
                              void* d_out, int out_size, void* d_ws, size_t ws_size,
                              hipStream_t stream)
{
    const float* x    = (const float*)d_in[0];
    const float* n1g  = (const float*)d_in[1];
    const float* n1b  = (const float*)d_in[2];
    const float* cw   = (const float*)d_in[3];
    const float* cb   = (const float*)d_in[4];
    const float* ipw  = (const float*)d_in[5];
    const float* scw  = (const float*)d_in[6];
    const float* scb  = (const float*)d_in[7];
    const float* xpw  = (const float*)d_in[8];
    const float* dtw  = (const float*)d_in[9];
    const float* dtb  = (const float*)d_in[10];
    const float* alog = (const float*)d_in[11];
    const float* dp   = (const float*)d_in[12];
    const float* opw  = (const float*)d_in[13];
    const float* n2g  = (const float*)d_in[14];
    const float* n2b  = (const float*)d_in[15];
    const float* w1   = (const float*)d_in[16];
    const float* b1   = (const float*)d_in[17];
    const float* w2   = (const float*)d_in[18];
    const float* b2   = (const float*)d_in[19];
    float* out = (float*)d_out;

    // Workspace layout (floats)
    float* ws   = (float*)d_ws;
    float* h1   = ws;                    // 4096*256  (reused: scan P/Hinit, LN2 out)
    float* hm   = h1 + 1048576;          // 4096*256
    float* xz   = hm + 1048576;          // 4096*1024 (reused as MLP mid)
    float* u    = xz + 4194304;          // 4096*512
    float* dbl  = u + 2097152;           // 4096*80
    float* dt   = dbl + 327680;          // 4096*512
    float* yg   = dt + 2097152;          // 4096*512
    float* hres = yg + 2097152;          // 4096*256  (reused: scan Q)
    float* mid  = xz;                    // alias: xz dead after scan

    // Scan scratch aliases (dead regions during the scan phase):
    // P/Hinit needs 4*512*16*32 = 1,048,576 floats -> h1 (dead after kernel 3)
    // Q same size -> hres (first real write is kernel 8, after scan)
    float* P = h1;
    float* Q = hres;

    // 1. LN1
    ln_kernel<<<MROWS, 256, 0, stream>>>(x, n1g, n1b, h1);
    // 2. conv3 + add
    conv3_add_kernel<<<MROWS, 256, 0, stream>>>(h1, cw, cb, hm);
    // 3. in_proj: xz = hm @ ipw^T  [4096,1024,256]
    gemm_nt<EPI_NONE><<<dim3(64, 16), 256, 0, stream>>>(
        hm, 256, ipw, 256, xz, 1024, MROWS, 1024, 256, nullptr, nullptr, 0);
    // 4. causal conv4 + silu
    conv4_silu_kernel<<<8192, 256, 0, stream>>>(xz, scw, scb, u);
    // 5. x_proj: dbl = u @ xpw^T  [4096,80,512]
    gemm_nt<EPI_NONE><<<dim3(64, 2), 256, 0, stream>>>(
        u, 512, xpw, 512, dbl, 80, MROWS, 80, 512, nullptr, nullptr, 0);
    // 6. dt_proj + softplus: dt = softplus(dbl[:, :16] @ dtw^T + dtb)
    gemm_nt<EPI_SOFTPLUS><<<dim3(64, 8), 256, 0, stream>>>(
        dbl, 80, dtw, 16, dt, 512, MROWS, 512, 16, dtb, nullptr, 0);
    // 7. chunked selective scan + gating
    scan_s1<<<4096, 256, 0, stream>>>(dt, u, dbl, alog, P, Q);
    scan_s2<<<256, 256, 0, stream>>>(P, Q);
    scan_s3<<<4096, 256, 0, stream>>>(dt, u, dbl, alog, dp, xz, P, yg);
    // 8. out_proj + residual: hres = yg @ opw^T + x
    gemm_nt<EPI_RES><<<dim3(64, 4), 256, 0, stream>>>(
        yg, 512, opw, 512, hres, 256, MROWS, 256, 512, nullptr, x, 256);
    // 9. LN2
    ln_kernel<<<MROWS, 256, 0, stream>>>(hres, n2g, n2b, h1);
    // 10. MLP1 + gelu: mid = gelu(h1 @ w1^T + b1)
    gemm_nt<EPI_GELU><<<dim3(64, 16), 256, 0, stream>>>(
        h1, 256, w1, 256, mid, 1024, MROWS, 1024, 256, b1, nullptr, 0);
    // 11. MLP2 + bias + residual: out = mid @ w2^T + b2 + hres
    gemm_nt<EPI_BIAS_RES><<<dim3(64, 4), 256, 0, stream>>>(
        mid, 1024, w2, 1024, out, 256, MROWS, 256, 1024, b2, hres, 256);
}

// Round 3
// 324.464 us; speedup vs baseline: 3.3160x; 1.3955x over previous
//
#include <hip/hip_runtime.h>
#include <hip/hip_bf16.h>
#include <math.h>

// Problem constants
#define BATCH 4
#define LSEQ  1024
#define DIM   256
#define ESZ   512      // E = 2*DIM
#define NST   32       // D_STATE
#define RNK   16       // DT_RANK
#define MROWS 4096     // B*L
#define NCH   32       // scan chunks
#define CHL   32       // chunk length (NCH*CHL == LSEQ)

typedef __attribute__((ext_vector_type(8))) short bf16x8;
typedef __attribute__((ext_vector_type(4))) float f32x4;

// ---------------------------------------------------------------------------
// fp32 -> bf16 conversion (vector-4). n4 = count/4.
// ---------------------------------------------------------------------------
__global__ __launch_bounds__(256) void f2bf4(
    const float* __restrict__ s, __hip_bfloat16* __restrict__ d, int n4)
{
    int i = blockIdx.x * 256 + threadIdx.x;
    if (i >= n4) return;
    float4 v = ((const float4*)s)[i];
    union { __hip_bfloat16 h[4]; short4 s4; } u;
    u.h[0] = __float2bfloat16(v.x);
    u.h[1] = __float2bfloat16(v.y);
    u.h[2] = __float2bfloat16(v.z);
    u.h[3] = __float2bfloat16(v.w);
    ((short4*)d)[i] = u.s4;
}

// ---------------------------------------------------------------------------
// LayerNorm over last dim (=256). One block (256 thr) per row.
// ---------------------------------------------------------------------------
template <int OUT_BF16>
__global__ __launch_bounds__(256) void ln_kernel(
    const float* __restrict__ x, const float* __restrict__ g,
    const float* __restrict__ b, void* __restrict__ yo)
{
    const int row = blockIdx.x;
    const int tid = threadIdx.x;
    float v = x[row * DIM + tid];
    float s = v, s2 = v * v;
    #pragma unroll
    for (int o = 32; o > 0; o >>= 1) {
        s  += __shfl_down(s,  o, 64);
        s2 += __shfl_down(s2, o, 64);
    }
    __shared__ float ls[4], ls2[4];
    if ((tid & 63) == 0) { ls[tid >> 6] = s; ls2[tid >> 6] = s2; }
    __syncthreads();
    float ts  = ls[0]  + ls[1]  + ls[2]  + ls[3];
    float ts2 = ls2[0] + ls2[1] + ls2[2] + ls2[3];
    float mean = ts * (1.f / DIM);
    float var  = ts2 * (1.f / DIM) - mean * mean;
    float inv  = rsqrtf(var + 1e-5f);
    float out  = (v - mean) * inv * g[tid] + b[tid];
    if (OUT_BF16)
        ((__hip_bfloat16*)yo)[row * DIM + tid] = __float2bfloat16(out);
    else
        ((float*)yo)[row * DIM + tid] = out;
}

// ---------------------------------------------------------------------------
// dwconv window-3 pad(1,1) + bias + residual add -> bf16: hm = conv3(h1)+cb+h1
// ---------------------------------------------------------------------------
__global__ __launch_bounds__(256) void conv3_add_kernel(
    const float* __restrict__ h1, const float* __restrict__ w,
    const float* __restrict__ cb, __hip_bfloat16* __restrict__ hm)
{
    const int i  = blockIdx.x * 256 + threadIdx.x;   // over 4096*256
    const int d  = i & (DIM - 1);
    const int bl = i >> 8;
    const int l  = bl & (LSEQ - 1);
    float c   = h1[i];
    float acc = w[d * 3 + 1] * c + cb[d] + c;
    if (l > 0)        acc += w[d * 3 + 0] * h1[i - DIM];
    if (l < LSEQ - 1) acc += w[d * 3 + 2] * h1[i + DIM];
    hm[i] = __float2bfloat16(acc);
}

// ---------------------------------------------------------------------------
// causal dwconv window-4 pad(3,0) + bias + SiLU.  xin = xz[:, :512]
// ---------------------------------------------------------------------------
__global__ __launch_bounds__(256) void conv4_silu_kernel(
    const float* __restrict__ xz, const float* __restrict__ w,
    const float* __restrict__ cb, float* __restrict__ u)
{
    const int i  = blockIdx.x * 256 + threadIdx.x;   // over 4096*512
    const int e  = i & (ESZ - 1);
    const int bl = i >> 9;
    const int l  = bl & (LSEQ - 1);
    float acc = cb[e];
    #pragma unroll
    for (int k = 0; k < 4; ++k) {
        int ls = l + k - 3;
        if (ls >= 0) acc += w[e * 4 + k] * xz[(long)(bl + k - 3) * 1024 + e];
    }
    float sv = acc / (1.f + __expf(-acc));
    u[(long)bl * ESZ + e] = sv;
}

// ---------------------------------------------------------------------------
// Epilogue ids
// ---------------------------------------------------------------------------
#define EPI_NONE      0
#define EPI_SOFTPLUS  1
#define EPI_GELU      2
#define EPI_RES       3
#define EPI_BIAS_RES  4

// ---------------------------------------------------------------------------
// bf16 MFMA GEMM: C[M,N] = A[M,K] @ W[N,K]^T  (+ epilogue)
// 256 threads = 4 waves. BK=64. BM in {64,128}, BN=128.
// mfma_f32_16x16x32_bf16 layouts (m89-verified):
//   A-frag: lane holds A[m=lane&15][k=(lane>>4)*8 + j]
//   B-frag: lane holds B[k=(lane>>4)*8 + j][n=lane&15]  (B = W^T)
//   C/D:    col=lane&15, row=(lane>>4)*4 + reg
// ---------------------------------------------------------------------------
template <int BM, int BN, int EPI, int OUT_BF16>
__global__ __launch_bounds__(256) void gemm_mfma(
    const __hip_bfloat16* __restrict__ A, int lda,
    const __hip_bfloat16* __restrict__ W, int ldw,
    void* __restrict__ Cout, int ldc, int K,
    const float* __restrict__ bias,
    const float* __restrict__ res, int ldres)
{
    constexpr int BK = 64;
    constexpr int LS = BK + 8;           // LDS row stride (bf16), pad breaks stride-64
    constexpr int WAVES_M = BM / 64;
    constexpr int WAVES_N = 4 / WAVES_M;
    constexpr int WTN = BN / WAVES_N;    // 64 (BM=128) or 32 (BM=64)
    constexpr int AMF = 4;               // 64/16 m-frags per wave
    constexpr int BNF = WTN / 16;        // 4 or 2 n-frags per wave
    constexpr int AR = BM / 32;          // A staging rounds
    constexpr int BR = BN / 32;          // W staging rounds

    __shared__ __hip_bfloat16 As[BM * LS];
    __shared__ __hip_bfloat16 Ws[BN * LS];

    const int tid  = threadIdx.x;
    const int lane = tid & 63;
    const int wave = tid >> 6;
    const int wm   = (wave / WAVES_N) * 64;
    const int wn   = (wave % WAVES_N) * WTN;
    const int m0   = blockIdx.x * BM;
    const int n0   = blockIdx.y * BN;
    const int srow = tid >> 3;           // 0..31
    const int scol = (tid & 7) * 8;      // 0..56 (bf16 units, 16B chunks)
    const int q    = lane >> 4;          // k-quad
    const int lr   = lane & 15;

    f32x4 acc[AMF][BNF];
    #pragma unroll
    for (int i = 0; i < AMF; ++i)
        #pragma unroll
        for (int j = 0; j < BNF; ++j)
            acc[i][j] = (f32x4){0.f, 0.f, 0.f, 0.f};

    const __hip_bfloat16* Ab = A + (long)m0 * lda;
    const __hip_bfloat16* Wb = W + (long)n0 * ldw;

    for (int k0 = 0; k0 < K; k0 += BK) {
        float4 ar[AR], wr[BR];
        #pragma unroll
        for (int r = 0; r < AR; ++r)
            ar[r] = *(const float4*)(Ab + (long)(r * 32 + srow) * lda + k0 + scol);
        #pragma unroll
        for (int r = 0; r < BR; ++r)
            wr[r] = *(const float4*)(Wb + (long)(r * 32 + srow) * ldw + k0 + scol);
        __syncthreads();
        #pragma unroll
        for (int r = 0; r < AR; ++r)
            *(float4*)(&As[(r * 32 + srow) * LS + scol]) = ar[r];
        #pragma unroll
        for (int r = 0; r < BR; ++r)
            *(float4*)(&Ws[(r * 32 + srow) * LS + scol]) = wr[r];
        __syncthreads();
        #pragma unroll
        for (int ks = 0; ks < 2; ++ks) {
            bf16x8 af[AMF], bfr[BNF];
            #pragma unroll
            for (int i = 0; i < AMF; ++i)
                af[i] = *(const bf16x8*)(&As[(wm + i * 16 + lr) * LS + ks * 32 + q * 8]);
            #pragma unroll
            for (int j = 0; j < BNF; ++j)
                bfr[j] = *(const bf16x8*)(&Ws[(wn + j * 16 + lr) * LS + ks * 32 + q * 8]);
            #pragma unroll
            for (int i = 0; i < AMF; ++i)
                #pragma unroll
                for (int j = 0; j < BNF; ++j)
                    acc[i][j] = __builtin_amdgcn_mfma_f32_16x16x32_bf16(
                        af[i], bfr[j], acc[i][j], 0, 0, 0);
        }
    }

    #pragma unroll
    for (int i = 0; i < AMF; ++i) {
        #pragma unroll
        for (int j = 0; j < BNF; ++j) {
            const int col  = n0 + wn + j * 16 + lr;
            const int rowb = m0 + wm + i * 16 + q * 4;
            #pragma unroll
            for (int r = 0; r < 4; ++r) {
                const int row = rowb + r;
                float v = acc[i][j][r];
                if (EPI == EPI_GELU) {
                    v += bias[col];
                    v = 0.5f * v * (1.f + erff(v * 0.70710678118654752f));
                } else if (EPI == EPI_RES) {
                    v += res[(long)row * ldres + col];
                } else if (EPI == EPI_BIAS_RES) {
                    v += bias[col] + res[(long)row * ldres + col];
                }
                if (OUT_BF16)
                    ((__hip_bfloat16*)Cout)[(long)row * ldc + col] = __float2bfloat16(v);
                else
                    ((float*)Cout)[(long)row * ldc + col] = v;
            }
        }
    }
}

// ---------------------------------------------------------------------------
// Generic fp32 GEMM (kept for small/odd shapes): C[M,N] = A[M,K] @ W[N,K]^T
// ---------------------------------------------------------------------------
template <int EPI, int OUT_BF16>
__global__ __launch_bounds__(256) void gemm_nt(
    const float* __restrict__ A, int lda,
    const float* __restrict__ W, int ldw,
    void* __restrict__ Cv, int ldc,
    int M, int N, int K,
    const float* __restrict__ bias,
    const float* __restrict__ res, int ldres)
{
    __shared__ float As[16][68];
    __shared__ float Bs[16][68];
    const int tid = threadIdx.x;
    const int m0 = blockIdx.x * 64;
    const int n0 = blockIdx.y * 64;
    const int tx = tid & 15, ty = tid >> 4;
    const int lr = tid >> 2;
    const int lk = (tid & 3) << 2;

    const float* Ap = A + (m0 + lr) * lda + lk;
    const float* Wp = W + (n0 + lr) * ldw + lk;
    const bool wv = (n0 + lr) < N;

    float acc[4][4];
    #pragma unroll
    for (int i = 0; i < 4; ++i)
        #pragma unroll
        for (int j = 0; j < 4; ++j) acc[i][j] = 0.f;

    for (int k0 = 0; k0 < K; k0 += 16) {
        float4 av = *(const float4*)(Ap + k0);
        float4 wvv = wv ? *(const float4*)(Wp + k0) : make_float4(0.f, 0.f, 0.f, 0.f);
        __syncthreads();
        As[lk + 0][lr] = av.x;  As[lk + 1][lr] = av.y;
        As[lk + 2][lr] = av.z;  As[lk + 3][lr] = av.w;
        Bs[lk + 0][lr] = wvv.x; Bs[lk + 1][lr] = wvv.y;
        Bs[lk + 2][lr] = wvv.z; Bs[lk + 3][lr] = wvv.w;
        __syncthreads();
        #pragma unroll
        for (int k = 0; k < 16; ++k) {
            float a0 = As[k][ty * 4 + 0], a1 = As[k][ty * 4 + 1];
            float a2 = As[k][ty * 4 + 2], a3 = As[k][ty * 4 + 3];
            float b0 = Bs[k][tx * 4 + 0], b1 = Bs[k][tx * 4 + 1];
            float b2 = Bs[k][tx * 4 + 2], b3 = Bs[k][tx * 4 + 3];
            acc[0][0] += a0 * b0; acc[0][1] += a0 * b1; acc[0][2] += a0 * b2; acc[0][3] += a0 * b3;
            acc[1][0] += a1 * b0; acc[1][1] += a1 * b1; acc[1][2] += a1 * b2; acc[1][3] += a1 * b3;
            acc[2][0] += a2 * b0; acc[2][1] += a2 * b1; acc[2][2] += a2 * b2; acc[2][3] += a2 * b3;
            acc[3][0] += a3 * b0; acc[3][1] += a3 * b1; acc[3][2] += a3 * b2; acc[3][3] += a3 * b3;
        }
    }

    #pragma unroll
    for (int i = 0; i < 4; ++i) {
        const int mm = m0 + ty * 4 + i;
        const float* rrow = (EPI == EPI_RES || EPI == EPI_BIAS_RES)
                              ? res + (long)mm * ldres : nullptr;
        float v4[4];
        #pragma unroll
        for (int j = 0; j < 4; ++j) {
            const int nn = n0 + tx * 4 + j;
            float v = acc[i][j];
            if (EPI == EPI_SOFTPLUS) {
                v += bias[(nn < N) ? nn : 0];
                v = (v > 20.f) ? v : log1pf(__expf(v));
            } else if (EPI == EPI_GELU) {
                v += bias[(nn < N) ? nn : 0];
                v = 0.5f * v * (1.f + erff(v * 0.70710678118654752f));
            } else if (EPI == EPI_RES) {
                v += (nn < N) ? rrow[nn] : 0.f;
            } else if (EPI == EPI_BIAS_RES) {
                v += ((nn < N) ? bias[nn] : 0.f) + ((nn < N) ? rrow[nn] : 0.f);
            }
            v4[j] = v;
        }
        const int nbase = n0 + tx * 4;
        if (OUT_BF16) {
            __hip_bfloat16* crow = (__hip_bfloat16*)Cv + (long)mm * ldc;
            #pragma unroll
            for (int j = 0; j < 4; ++j)
                if (nbase + j < N) crow[nbase + j] = __float2bfloat16(v4[j]);
        } else {
            float* crow = (float*)Cv + (long)mm * ldc;
            if (nbase + 3 < N) {
                *(float4*)(crow + nbase) = make_float4(v4[0], v4[1], v4[2], v4[3]);
            } else {
                #pragma unroll
                for (int j = 0; j < 4; ++j)
                    if (nbase + j < N) crow[nbase + j] = v4[j];
            }
        }
    }
}

// ---------------------------------------------------------------------------
// Chunked parallel selective scan, "layout B": one lane owns one channel e
// and all 32 states in registers. No cross-lane ops. dt/u/z coalesced across
// lanes; B/C loads wave-uniform.
// Grid: B * NCH * (E/256) = 4*32*2 = 256 blocks of 256 threads.
// P/Q layout: [b][c][n][e] so per-n accesses coalesce over e.
// ---------------------------------------------------------------------------
__global__ __launch_bounds__(256) void scan_s1(
    const __hip_bfloat16* __restrict__ dt, const float* __restrict__ u,
    const float* __restrict__ dbl, const float* __restrict__ A_log,
    float* __restrict__ P, float* __restrict__ Q)
{
    const int e  = ((blockIdx.x & 1) << 8) + threadIdx.x;
    const int bc = blockIdx.x >> 1;
    const int c  = bc & (NCH - 1);
    const int b  = bc >> 5;

    float Aen[NST];
    #pragma unroll
    for (int qd = 0; qd < 8; ++qd) {
        float4 a4 = *(const float4*)(A_log + e * NST + qd * 4);
        Aen[qd * 4 + 0] = -__expf(a4.x);
        Aen[qd * 4 + 1] = -__expf(a4.y);
        Aen[qd * 4 + 2] = -__expf(a4.z);
        Aen[qd * 4 + 3] = -__expf(a4.w);
    }
    float Pv[NST], Qv[NST];
    #pragma unroll
    for (int n = 0; n < NST; ++n) { Pv[n] = 1.f; Qv[n] = 0.f; }

    const int base = b * LSEQ + c * CHL;
    #pragma unroll 2
    for (int t = 0; t < CHL; ++t) {
        const long bl = base + t;
        float ldt = __bfloat162float(dt[bl * ESZ + e]);
        float lu  = u[bl * ESZ + e];
        float xx  = ldt * lu;
        const float* bp = dbl + bl * 80 + 16;
        float bv[NST];
        #pragma unroll
        for (int qd = 0; qd < 8; ++qd) {
            float4 b4 = *(const float4*)(bp + qd * 4);
            bv[qd * 4 + 0] = b4.x; bv[qd * 4 + 1] = b4.y;
            bv[qd * 4 + 2] = b4.z; bv[qd * 4 + 3] = b4.w;
        }
        #pragma unroll
        for (int n = 0; n < NST; ++n) {
            float dA = __expf(ldt * Aen[n]);
            Pv[n] *= dA;
            Qv[n] = fmaf(dA, Qv[n], xx * bv[n]);
        }
    }
    const long pb = ((long)(b * NCH + c) * NST) * ESZ + e;
    #pragma unroll
    for (int n = 0; n < NST; ++n) {
        P[pb + (long)n * ESZ] = Pv[n];
        Q[pb + (long)n * ESZ] = Qv[n];
    }
}

// Sequential combine over chunks; writes Hinit (chunk-entry state) over P.
__global__ __launch_bounds__(256) void scan_s2(
    float* __restrict__ P, const float* __restrict__ Q)
{
    const int tg = blockIdx.x * 256 + threadIdx.x;   // 65536 = B*NST*E
    const int e  = tg & (ESZ - 1);
    const int n  = (tg >> 9) & (NST - 1);
    const int b  = tg >> 14;
    float h = 0.f;
    #pragma unroll
    for (int c = 0; c < NCH; ++c) {
        const long idx = ((long)(b * NCH + c) * NST + n) * ESZ + e;
        float Pv = P[idx];
        float Qv = Q[idx];
        P[idx] = h;
        h = fmaf(Pv, h, Qv);
    }
}

__global__ __launch_bounds__(256) void scan_s3(
    const __hip_bfloat16* __restrict__ dt, const float* __restrict__ u,
    const float* __restrict__ dbl, const float* __restrict__ A_log,
    const float* __restrict__ Dp, const float* __restrict__ xz,
    const float* __restrict__ H, __hip_bfloat16* __restrict__ yg)
{
    const int e  = ((blockIdx.x & 1) << 8) + threadIdx.x;
    const int bc = blockIdx.x >> 1;
    const int c  = bc & (NCH - 1);
    const int b  = bc >> 5;

    float Aen[NST];
    #pragma unroll
    for (int qd = 0; qd < 8; ++qd) {
        float4 a4 = *(const float4*)(A_log + e * NST + qd * 4);
        Aen[qd * 4 + 0] = -__expf(a4.x);
        Aen[qd * 4 + 1] = -__expf(a4.y);
        Aen[qd * 4 + 2] = -__expf(a4.z);
        Aen[qd * 4 + 3] = -__expf(a4.w);
    }
    float h[NST];
    const long pb = ((long)(b * NCH + c) * NST) * ESZ + e;
    #pragma unroll
    for (int n = 0; n < NST; ++n) h[n] = H[pb + (long)n * ESZ];
    const float dpe = Dp[e];

    const int base = b * LSEQ + c * CHL;
    #pragma unroll 2
    for (int t = 0; t < CHL; ++t) {
        const long bl = base + t;
        float ldt = __bfloat162float(dt[bl * ESZ + e]);
        float lu  = u[bl * ESZ + e];
        float xx  = ldt * lu;
        const float* bp = dbl + bl * 80 + 16;
        const float* cp = dbl + bl * 80 + 48;
        float bv[NST], cv[NST];
        #pragma unroll
        for (int qd = 0; qd < 8; ++qd) {
            float4 b4 = *(const float4*)(bp + qd * 4);
            float4 c4 = *(const float4*)(cp + qd * 4);
            bv[qd * 4 + 0] = b4.x; bv[qd * 4 + 1] = b4.y;
            bv[qd * 4 + 2] = b4.z; bv[qd * 4 + 3] = b4.w;
            cv[qd * 4 + 0] = c4.x; cv[qd * 4 + 1] = c4.y;
            cv[qd * 4 + 2] = c4.z; cv[qd * 4 + 3] = c4.w;
        }
        float y = 0.f;
        #pragma unroll
        for (int n = 0; n < NST; ++n) {
            float dA = __expf(ldt * Aen[n]);
            h[n] = fmaf(dA, h[n], xx * bv[n]);
            y = fmaf(h[n], cv[n], y);
        }
        y += lu * dpe;
        float z = xz[bl * 1024 + ESZ + e];
        float g = z / (1.f + __expf(-z));
        yg[bl * ESZ + e] = __float2bfloat16(y * g);
    }
}

// ---------------------------------------------------------------------------
extern "C" void kernel_launch(void* const* d_in, const int* in_sizes, int n_in,
                              void* d_out, int out_size, void* d_ws, size_t ws_size,
                              hipStream_t stream)
{
    const float* x    = (const float*)d_in[0];
    const float* n1g  = (const float*)d_in[1];
    const float* n1b  = (const float*)d_in[2];
    const float* cw   = (const float*)d_in[3];
    const float* cb   = (const float*)d_in[4];
    const float* ipw  = (const float*)d_in[5];
    const float* scw  = (const float*)d_in[6];
    const float* scb  = (const float*)d_in[7];
    const float* xpw  = (const float*)d_in[8];
    const float* dtw  = (const float*)d_in[9];
    const float* dtbi = (const float*)d_in[10];
    const float* alog = (const float*)d_in[11];
    const float* dp   = (const float*)d_in[12];
    const float* opw  = (const float*)d_in[13];
    const float* n2g  = (const float*)d_in[14];
    const float* n2b  = (const float*)d_in[15];
    const float* w1   = (const float*)d_in[16];
    const float* b1   = (const float*)d_in[17];
    const float* w2   = (const float*)d_in[18];
    const float* b2   = (const float*)d_in[19];
    float* out = (float*)d_out;

    // Workspace layout (float units). Total 12,320,768 f = 49.3 MB.
    // Aliases: Q = [h1|ygb] (2,097,152 f); P = [hres|h1b|hmb]; midb = xz[0:2M].
    float* ws = (float*)d_ws;
    float*          h1   = ws;                                   // 1,048,576 f
    __hip_bfloat16* ygb  = (__hip_bfloat16*)(ws + 1048576);      // 1,048,576 f
    float*          hres = ws + 2097152;                         // 1,048,576 f
    __hip_bfloat16* h1b  = (__hip_bfloat16*)(ws + 3145728);      //   524,288 f
    __hip_bfloat16* hmb  = (__hip_bfloat16*)(ws + 3670016);      //   524,288 f
    float*          xz   = ws + 4194304;                         // 4,194,304 f
    float*          u    = ws + 8388608;                         // 2,097,152 f
    float*          dbl  = ws + 10485760;                        //   327,680 f
    __hip_bfloat16* dtb  = (__hip_bfloat16*)(ws + 10813440);     // 1,048,576 f
    __hip_bfloat16* ipwb = (__hip_bfloat16*)(ws + 11862016);     //   131,072 f
    __hip_bfloat16* opwb = (__hip_bfloat16*)(ws + 11993088);     //    65,536 f
    __hip_bfloat16* w1b  = (__hip_bfloat16*)(ws + 12058624);     //   131,072 f
    __hip_bfloat16* w2b  = (__hip_bfloat16*)(ws + 12189696);     //   131,072 f
    float* Q = ws;                     // spans h1+ygb   (dead before s3 write)
    float* P = ws + 2097152;           // spans hres+h1b+hmb (all written >= k8)
    __hip_bfloat16* midb = (__hip_bfloat16*)(ws + 4194304);      // alias xz

    // 0. weight conversions to bf16
    f2bf4<<<256, 256, 0, stream>>>(ipw, ipwb, 65536);   // 1024x256
    f2bf4<<<128, 256, 0, stream>>>(opw, opwb, 32768);   // 256x512
    f2bf4<<<256, 256, 0, stream>>>(w1,  w1b,  65536);   // 1024x256
    f2bf4<<<256, 256, 0, stream>>>(w2,  w2b,  65536);   // 256x1024
    // 1. LN1 (fp32 out)
    ln_kernel<0><<<MROWS, 256, 0, stream>>>(x, n1g, n1b, h1);
    // 2. conv3 + residual -> bf16
    conv3_add_kernel<<<MROWS, 256, 0, stream>>>(h1, cw, cb, hmb);
    // 3. in_proj (MFMA): xz = hm @ ipw^T  [4096,1024,256]
    gemm_mfma<128, 128, EPI_NONE, 0><<<dim3(32, 8), 256, 0, stream>>>(
        hmb, 256, ipwb, 256, xz, 1024, 256, nullptr, nullptr, 0);
    // 4. causal conv4 + silu
    conv4_silu_kernel<<<8192, 256, 0, stream>>>(xz, scw, scb, u);
    // 5. x_proj (fp32): dbl = u @ xpw^T  [4096,80,512]
    gemm_nt<EPI_NONE, 0><<<dim3(64, 2), 256, 0, stream>>>(
        u, 512, xpw, 512, dbl, 80, MROWS, 80, 512, nullptr, nullptr, 0);
    // 6. dt_proj + softplus -> bf16: dt = softplus(dbl[:,:16] @ dtw^T + dtb)
    gemm_nt<EPI_SOFTPLUS, 1><<<dim3(64, 8), 256, 0, stream>>>(
        dbl, 80, dtw, 16, dtb, 512, MROWS, 512, 16, dtbi, nullptr, 0);
    // 7. chunked selective scan + gating -> bf16 yg
    scan_s1<<<256, 256, 0, stream>>>(dtb, u, dbl, alog, P, Q);
    scan_s2<<<256, 256, 0, stream>>>(P, Q);
    scan_s3<<<256, 256, 0, stream>>>(dtb, u, dbl, alog, dp, xz, P, ygb);
    // 8. out_proj (MFMA) + residual: hres = yg @ opw^T + x
    gemm_mfma<64, 128, EPI_RES, 0><<<dim3(64, 2), 256, 0, stream>>>(
        ygb, 512, opwb, 512, hres, 256, 512, nullptr, x, 256);
    // 9. LN2 -> bf16
    ln_kernel<1><<<MROWS, 256, 0, stream>>>(hres, n2g, n2b, h1b);
    // 10. MLP1 (MFMA) + gelu -> bf16 mid
    gemm_mfma<128, 128, EPI_GELU, 1><<<dim3(32, 8), 256, 0, stream>>>(
        h1b, 256, w1b, 256, midb, 1024, 256, b1, nullptr, 0);
    // 11. MLP2 (MFMA) + bias + residual: out = mid @ w2^T + b2 + hres
    gemm_mfma<64, 128, EPI_BIAS_RES, 0><<<dim3(64, 2), 256, 0, stream>>>(
        midb, 1024, w2b, 1024, out, 256, 1024, b2, hres, 256);
}

// Round 4
// 313.960 us; speedup vs baseline: 3.4269x; 1.0335x over previous
//
#include <hip/hip_runtime.h>
#include <hip/hip_bf16.h>
#include <math.h>

// Problem constants
#define BATCH 4
#define LSEQ  1024
#define DIM   256
#define ESZ   512      // E = 2*DIM
#define NST   32       // D_STATE
#define RNK   16       // DT_RANK
#define MROWS 4096     // B*L
#define NCH   64       // scan chunks
#define CHL   16       // chunk length (NCH*CHL == LSEQ)

typedef __attribute__((ext_vector_type(8))) short bf16x8;
typedef __attribute__((ext_vector_type(4))) float f32x4;

// ---------------------------------------------------------------------------
// All weight fp32->bf16 conversions in ONE kernel (launch-gap economy).
// Segments (float4 units): ipw 65536 | opw 32768 | w1 65536 | w2 65536 | xpw 10240
// ---------------------------------------------------------------------------
__global__ __launch_bounds__(256) void convert_weights(
    const float* __restrict__ ipw, const float* __restrict__ opw,
    const float* __restrict__ w1,  const float* __restrict__ w2,
    const float* __restrict__ xpw, __hip_bfloat16* __restrict__ dst)
{
    int i = blockIdx.x * 256 + threadIdx.x;   // over 239616 float4s
    if (i >= 239616) return;
    const float* s; int off;
    if      (i < 65536)  { s = ipw; off = i; }
    else if (i < 98304)  { s = opw; off = i - 65536; }
    else if (i < 163840) { s = w1;  off = i - 98304; }
    else if (i < 229376) { s = w2;  off = i - 163840; }
    else                 { s = xpw; off = i - 229376; }
    float4 v = ((const float4*)s)[off];
    union { __hip_bfloat16 h[4]; short4 s4; } u;
    u.h[0] = __float2bfloat16(v.x);
    u.h[1] = __float2bfloat16(v.y);
    u.h[2] = __float2bfloat16(v.z);
    u.h[3] = __float2bfloat16(v.w);
    ((short4*)dst)[i] = u.s4;
}

// ---------------------------------------------------------------------------
// Fused LN1 + dwconv3 + residual -> bf16.
// Block = one row (b,l); recomputes LN of rows l-1,l+1 (halo) in-block.
// hm[r,d] = w[d,1]*ln_c + (l>0)w[d,0]*ln_l + (l<1023)w[d,2]*ln_r + cb[d] + ln_c
// ---------------------------------------------------------------------------
__global__ __launch_bounds__(256) void ln1_conv3_kernel(
    const float* __restrict__ x, const float* __restrict__ g,
    const float* __restrict__ b, const float* __restrict__ cw,
    const float* __restrict__ cb, __hip_bfloat16* __restrict__ hm)
{
    const int row = blockIdx.x;
    const int l   = row & (LSEQ - 1);
    const int d   = threadIdx.x;
    const float gc = g[d], bc = b[d];

    float xc = x[row * DIM + d];
    float xl = (l > 0)        ? x[(row - 1) * DIM + d] : 0.f;
    float xr = (l < LSEQ - 1) ? x[(row + 1) * DIM + d] : 0.f;

    float a[6] = { xc, xc * xc, xl, xl * xl, xr, xr * xr };
    #pragma unroll
    for (int o = 32; o > 0; o >>= 1)
        #pragma unroll
        for (int j = 0; j < 6; ++j) a[j] += __shfl_down(a[j], o, 64);
    __shared__ float red[4][6];
    if ((d & 63) == 0)
        #pragma unroll
        for (int j = 0; j < 6; ++j) red[d >> 6][j] = a[j];
    __syncthreads();
    float t[6];
    #pragma unroll
    for (int j = 0; j < 6; ++j)
        t[j] = red[0][j] + red[1][j] + red[2][j] + red[3][j];

    auto ln = [&](float v, float s, float s2) {
        float m  = s * (1.f / DIM);
        float vr = s2 * (1.f / DIM) - m * m;
        return (v - m) * rsqrtf(vr + 1e-5f) * gc + bc;
    };
    float ln_c = ln(xc, t[0], t[1]);
    float acc  = cw[d * 3 + 1] * ln_c + cb[d] + ln_c;
    if (l > 0)        acc += cw[d * 3 + 0] * ln(xl, t[2], t[3]);
    if (l < LSEQ - 1) acc += cw[d * 3 + 2] * ln(xr, t[4], t[5]);
    hm[row * DIM + d] = __float2bfloat16(acc);
}

// ---------------------------------------------------------------------------
// Plain LayerNorm (used for LN2) -> bf16
// ---------------------------------------------------------------------------
__global__ __launch_bounds__(256) void ln_kernel(
    const float* __restrict__ x, const float* __restrict__ g,
    const float* __restrict__ b, __hip_bfloat16* __restrict__ y)
{
    const int row = blockIdx.x;
    const int tid = threadIdx.x;
    float v = x[row * DIM + tid];
    float s = v, s2 = v * v;
    #pragma unroll
    for (int o = 32; o > 0; o >>= 1) {
        s  += __shfl_down(s,  o, 64);
        s2 += __shfl_down(s2, o, 64);
    }
    __shared__ float ls[4], ls2[4];
    if ((tid & 63) == 0) { ls[tid >> 6] = s; ls2[tid >> 6] = s2; }
    __syncthreads();
    float ts  = ls[0]  + ls[1]  + ls[2]  + ls[3];
    float ts2 = ls2[0] + ls2[1] + ls2[2] + ls2[3];
    float mean = ts * (1.f / DIM);
    float var  = ts2 * (1.f / DIM) - mean * mean;
    float inv  = rsqrtf(var + 1e-5f);
    y[row * DIM + tid] =
        __float2bfloat16((v - mean) * inv * g[tid] + b[tid]);
}

// ---------------------------------------------------------------------------
// causal dwconv4 + SiLU -> bf16 ub only (scans recompute fp32 u from xz).
// ---------------------------------------------------------------------------
__global__ __launch_bounds__(256) void conv4_silu_kernel(
    const float* __restrict__ xz, const float* __restrict__ w,
    const float* __restrict__ cb, __hip_bfloat16* __restrict__ ub)
{
    const int i  = blockIdx.x * 256 + threadIdx.x;   // over 4096*512
    const int e  = i & (ESZ - 1);
    const int bl = i >> 9;
    const int l  = bl & (LSEQ - 1);
    float acc = cb[e];
    #pragma unroll
    for (int k = 0; k < 4; ++k) {
        int ls = l + k - 3;
        if (ls >= 0) acc += w[e * 4 + k] * xz[(long)(bl + k - 3) * 1024 + e];
    }
    float sv = acc / (1.f + __expf(-acc));
    ub[(long)bl * ESZ + e] = __float2bfloat16(sv);
}

// ---------------------------------------------------------------------------
// Epilogue ids
// ---------------------------------------------------------------------------
#define EPI_NONE      0
#define EPI_GELU      2
#define EPI_RES       3
#define EPI_BIAS_RES  4

// ---------------------------------------------------------------------------
// bf16 MFMA GEMM: C[M,N] = A[M,K] @ W[N,K]^T  (+ epilogue)
// ---------------------------------------------------------------------------
template <int BM, int BN, int EPI, int OUT_BF16>
__global__ __launch_bounds__(256) void gemm_mfma(
    const __hip_bfloat16* __restrict__ A, int lda,
    const __hip_bfloat16* __restrict__ W, int ldw,
    void* __restrict__ Cout, int ldc, int K,
    const float* __restrict__ bias,
    const float* __restrict__ res, int ldres)
{
    constexpr int BK = 64;
    constexpr int LS = BK + 8;
    constexpr int WAVES_M = BM / 64;
    constexpr int WAVES_N = 4 / WAVES_M;
    constexpr int WTN = BN / WAVES_N;
    constexpr int AMF = 4;
    constexpr int BNF = WTN / 16;
    constexpr int AR = BM / 32;
    constexpr int BR = BN / 32;

    __shared__ __hip_bfloat16 As[BM * LS];
    __shared__ __hip_bfloat16 Ws[BN * LS];

    const int tid  = threadIdx.x;
    const int lane = tid & 63;
    const int wave = tid >> 6;
    const int wm   = (wave / WAVES_N) * 64;
    const int wn   = (wave % WAVES_N) * WTN;
    const int m0   = blockIdx.x * BM;
    const int n0   = blockIdx.y * BN;
    const int srow = tid >> 3;
    const int scol = (tid & 7) * 8;
    const int q    = lane >> 4;
    const int lr   = lane & 15;

    f32x4 acc[AMF][BNF];
    #pragma unroll
    for (int i = 0; i < AMF; ++i)
        #pragma unroll
        for (int j = 0; j < BNF; ++j)
            acc[i][j] = (f32x4){0.f, 0.f, 0.f, 0.f};

    const __hip_bfloat16* Ab = A + (long)m0 * lda;
    const __hip_bfloat16* Wb = W + (long)n0 * ldw;

    for (int k0 = 0; k0 < K; k0 += BK) {
        float4 ar[AR], wr[BR];
        #pragma unroll
        for (int r = 0; r < AR; ++r)
            ar[r] = *(const float4*)(Ab + (long)(r * 32 + srow) * lda + k0 + scol);
        #pragma unroll
        for (int r = 0; r < BR; ++r)
            wr[r] = *(const float4*)(Wb + (long)(r * 32 + srow) * ldw + k0 + scol);
        __syncthreads();
        #pragma unroll
        for (int r = 0; r < AR; ++r)
            *(float4*)(&As[(r * 32 + srow) * LS + scol]) = ar[r];
        #pragma unroll
        for (int r = 0; r < BR; ++r)
            *(float4*)(&Ws[(r * 32 + srow) * LS + scol]) = wr[r];
        __syncthreads();
        #pragma unroll
        for (int ks = 0; ks < 2; ++ks) {
            bf16x8 af[AMF], bfr[BNF];
            #pragma unroll
            for (int i = 0; i < AMF; ++i)
                af[i] = *(const bf16x8*)(&As[(wm + i * 16 + lr) * LS + ks * 32 + q * 8]);
            #pragma unroll
            for (int j = 0; j < BNF; ++j)
                bfr[j] = *(const bf16x8*)(&Ws[(wn + j * 16 + lr) * LS + ks * 32 + q * 8]);
            #pragma unroll
            for (int i = 0; i < AMF; ++i)
                #pragma unroll
                for (int j = 0; j < BNF; ++j)
                    acc[i][j] = __builtin_amdgcn_mfma_f32_16x16x32_bf16(
                        af[i], bfr[j], acc[i][j], 0, 0, 0);
        }
    }

    #pragma unroll
    for (int i = 0; i < AMF; ++i) {
        #pragma unroll
        for (int j = 0; j < BNF; ++j) {
            const int col  = n0 + wn + j * 16 + lr;
            const int rowb = m0 + wm + i * 16 + q * 4;
            #pragma unroll
            for (int r = 0; r < 4; ++r) {
                const int row = rowb + r;
                float v = acc[i][j][r];
                if (EPI == EPI_GELU) {
                    v += bias[col];
                    v = 0.5f * v * (1.f + erff(v * 0.70710678118654752f));
                } else if (EPI == EPI_RES) {
                    v += res[(long)row * ldres + col];
                } else if (EPI == EPI_BIAS_RES) {
                    v += bias[col] + res[(long)row * ldres + col];
                }
                if (OUT_BF16)
                    ((__hip_bfloat16*)Cout)[(long)row * ldc + col] = __float2bfloat16(v);
                else
                    ((float*)Cout)[(long)row * ldc + col] = v;
            }
        }
    }
}

// ---------------------------------------------------------------------------
// x_proj MFMA: dbl[4096,80] = ub[4096,512] @ xpwb[80,512]^T  (N=80 = 5 frags)
// BM=64 (wave m-slices of 16), BN=80 full, BK=64, grid 64 blocks.
// ---------------------------------------------------------------------------
__global__ __launch_bounds__(256) void xproj_mfma(
    const __hip_bfloat16* __restrict__ A,
    const __hip_bfloat16* __restrict__ W,
    float* __restrict__ C)
{
    constexpr int LS = 72;
    __shared__ __hip_bfloat16 As[64 * LS];
    __shared__ __hip_bfloat16 Ws[80 * LS];
    const int tid  = threadIdx.x;
    const int lane = tid & 63;
    const int wave = tid >> 6;
    const int wm   = wave * 16;
    const int m0   = blockIdx.x * 64;
    const int srow = tid >> 3;
    const int scol = (tid & 7) * 8;
    const int q    = lane >> 4;
    const int lr   = lane & 15;

    f32x4 acc[5];
    #pragma unroll
    for (int j = 0; j < 5; ++j) acc[j] = (f32x4){0.f, 0.f, 0.f, 0.f};

    for (int k0 = 0; k0 < 512; k0 += 64) {
        float4 ar[2], wr[3];
        #pragma unroll
        for (int r = 0; r < 2; ++r)
            ar[r] = *(const float4*)(A + (long)(m0 + r * 32 + srow) * 512 + k0 + scol);
        #pragma unroll
        for (int r = 0; r < 3; ++r) {
            int row = r * 32 + srow;
            wr[r] = (row < 80)
                ? *(const float4*)(W + (long)row * 512 + k0 + scol)
                : make_float4(0.f, 0.f, 0.f, 0.f);
        }
        __syncthreads();
        #pragma unroll
        for (int r = 0; r < 2; ++r)
            *(float4*)(&As[(r * 32 + srow) * LS + scol]) = ar[r];
        #pragma unroll
        for (int r = 0; r < 3; ++r) {
            int row = r * 32 + srow;
            if (row < 80) *(float4*)(&Ws[row * LS + scol]) = wr[r];
        }
        __syncthreads();
        #pragma unroll
        for (int ks = 0; ks < 2; ++ks) {
            bf16x8 af = *(const bf16x8*)(&As[(wm + lr) * LS + ks * 32 + q * 8]);
            #pragma unroll
            for (int j = 0; j < 5; ++j) {
                bf16x8 bf = *(const bf16x8*)(&Ws[(j * 16 + lr) * LS + ks * 32 + q * 8]);
                acc[j] = __builtin_amdgcn_mfma_f32_16x16x32_bf16(af, bf, acc[j], 0, 0, 0);
            }
        }
    }
    #pragma unroll
    for (int j = 0; j < 5; ++j)
        #pragma unroll
        for (int r = 0; r < 4; ++r)
            C[(long)(m0 + wm + q * 4 + r) * 80 + j * 16 + lr] = acc[j][r];
}

// ---------------------------------------------------------------------------
// Chunked parallel selective scan, layout B (lane owns channel e, 32 states
// in regs). u and dt recomputed on the fly (fp32-exact u from xz; dt from
// dbl[:, :16] dot dtw + softplus). NCH=64, CHL=16; grid 512 blocks.
// P/Q layout: [b][c][n][e].
// ---------------------------------------------------------------------------
__global__ __launch_bounds__(256) void scan_s1(
    const float* __restrict__ xz, const float* __restrict__ dbl,
    const float* __restrict__ A_log, const float* __restrict__ dtw,
    const float* __restrict__ dtb, const float* __restrict__ scw,
    const float* __restrict__ scb,
    float* __restrict__ P, float* __restrict__ Q)
{
    const int e  = ((blockIdx.x & 1) << 8) + threadIdx.x;
    const int bc = blockIdx.x >> 1;
    const int c  = bc & (NCH - 1);
    const int b  = bc >> 6;

    float Aen[NST];
    #pragma unroll
    for (int qd = 0; qd < 8; ++qd) {
        float4 a4 = *(const float4*)(A_log + e * NST + qd * 4);
        Aen[qd * 4 + 0] = -__expf(a4.x);
        Aen[qd * 4 + 1] = -__expf(a4.y);
        Aen[qd * 4 + 2] = -__expf(a4.z);
        Aen[qd * 4 + 3] = -__expf(a4.w);
    }
    float wt[RNK];
    #pragma unroll
    for (int qd = 0; qd < 4; ++qd) {
        float4 w4 = *(const float4*)(dtw + e * RNK + qd * 4);
        wt[qd * 4 + 0] = w4.x; wt[qd * 4 + 1] = w4.y;
        wt[qd * 4 + 2] = w4.z; wt[qd * 4 + 3] = w4.w;
    }
    const float dtbe = dtb[e];
    float cw4[4];
    #pragma unroll
    for (int k = 0; k < 4; ++k) cw4[k] = scw[e * 4 + k];
    const float cbe = scb[e];

    const int l0 = c * CHL;
    const long rowbase = ((long)b * LSEQ) * 1024 + e;
    float xw0, xw1, xw2;
    if (c == 0) { xw0 = xw1 = xw2 = 0.f; }
    else {
        xw0 = xz[rowbase + (long)(l0 - 3) * 1024];
        xw1 = xz[rowbase + (long)(l0 - 2) * 1024];
        xw2 = xz[rowbase + (long)(l0 - 1) * 1024];
    }

    float Pv[NST], Qv[NST];
    #pragma unroll
    for (int n = 0; n < NST; ++n) { Pv[n] = 1.f; Qv[n] = 0.f; }

    #pragma unroll 2
    for (int t = 0; t < CHL; ++t) {
        const int l = l0 + t;
        const long bl = (long)b * LSEQ + l;
        float xw3 = xz[rowbase + (long)l * 1024];
        float ua = cbe + cw4[0] * xw0 + cw4[1] * xw1 + cw4[2] * xw2 + cw4[3] * xw3;
        float u  = ua / (1.f + __expf(-ua));
        xw0 = xw1; xw1 = xw2; xw2 = xw3;

        const float* dr = dbl + bl * 80;
        float raw = dtbe;
        #pragma unroll
        for (int qd = 0; qd < 4; ++qd) {
            float4 d4 = *(const float4*)(dr + qd * 4);
            raw += wt[qd * 4 + 0] * d4.x + wt[qd * 4 + 1] * d4.y
                 + wt[qd * 4 + 2] * d4.z + wt[qd * 4 + 3] * d4.w;
        }
        float dt = (raw > 20.f) ? raw : log1pf(__expf(raw));
        float xx = dt * u;

        const float* bp = dr + 16;
        #pragma unroll
        for (int qd = 0; qd < 8; ++qd) {
            float4 b4 = *(const float4*)(bp + qd * 4);
            #pragma unroll
            for (int j = 0; j < 4; ++j) {
                const int n = qd * 4 + j;
                float bn = (j == 0) ? b4.x : (j == 1) ? b4.y : (j == 2) ? b4.z : b4.w;
                float dA = __expf(dt * Aen[n]);
                Pv[n] *= dA;
                Qv[n] = fmaf(dA, Qv[n], xx * bn);
            }
        }
    }
    const long pb = ((long)(b * NCH + c) * NST) * ESZ + e;
    #pragma unroll
    for (int n = 0; n < NST; ++n) {
        P[pb + (long)n * ESZ] = Pv[n];
        Q[pb + (long)n * ESZ] = Qv[n];
    }
}

// Sequential combine over chunks; writes Hinit (chunk-entry state) over P.
__global__ __launch_bounds__(256) void scan_s2(
    float* __restrict__ P, const float* __restrict__ Q)
{
    const int tg = blockIdx.x * 256 + threadIdx.x;   // 65536 = B*NST*E
    const int e  = tg & (ESZ - 1);
    const int n  = (tg >> 9) & (NST - 1);
    const int b  = tg >> 14;
    float h = 0.f;
    #pragma unroll 4
    for (int c = 0; c < NCH; ++c) {
        const long idx = ((long)(b * NCH + c) * NST + n) * ESZ + e;
        float Pv = P[idx];
        float Qv = Q[idx];
        P[idx] = h;
        h = fmaf(Pv, h, Qv);
    }
}

__global__ __launch_bounds__(256) void scan_s3(
    const float* __restrict__ xz, const float* __restrict__ dbl,
    const float* __restrict__ A_log, const float* __restrict__ dtw,
    const float* __restrict__ dtb, const float* __restrict__ scw,
    const float* __restrict__ scb, const float* __restrict__ Dp,
    const float* __restrict__ H, __hip_bfloat16* __restrict__ yg)
{
    const int e  = ((blockIdx.x & 1) << 8) + threadIdx.x;
    const int bc = blockIdx.x >> 1;
    const int c  = bc & (NCH - 1);
    const int b  = bc >> 6;

    float Aen[NST];
    #pragma unroll
    for (int qd = 0; qd < 8; ++qd) {
        float4 a4 = *(const float4*)(A_log + e * NST + qd * 4);
        Aen[qd * 4 + 0] = -__expf(a4.x);
        Aen[qd * 4 + 1] = -__expf(a4.y);
        Aen[qd * 4 + 2] = -__expf(a4.z);
        Aen[qd * 4 + 3] = -__expf(a4.w);
    }
    float wt[RNK];
    #pragma unroll
    for (int qd = 0; qd < 4; ++qd) {
        float4 w4 = *(const float4*)(dtw + e * RNK + qd * 4);
        wt[qd * 4 + 0] = w4.x; wt[qd * 4 + 1] = w4.y;
        wt[qd * 4 + 2] = w4.z; wt[qd * 4 + 3] = w4.w;
    }
    const float dtbe = dtb[e];
    float cw4[4];
    #pragma unroll
    for (int k = 0; k < 4; ++k) cw4[k] = scw[e * 4 + k];
    const float cbe = scb[e];
    const float dpe = Dp[e];

    float h[NST];
    const long pb = ((long)(b * NCH + c) * NST) * ESZ + e;
    #pragma unroll
    for (int n = 0; n < NST; ++n) h[n] = H[pb + (long)n * ESZ];

    const int l0 = c * CHL;
    const long rowbase = ((long)b * LSEQ) * 1024 + e;
    float xw0, xw1, xw2;
    if (c == 0) { xw0 = xw1 = xw2 = 0.f; }
    else {
        xw0 = xz[rowbase + (long)(l0 - 3) * 1024];
        xw1 = xz[rowbase + (long)(l0 - 2) * 1024];
        xw2 = xz[rowbase + (long)(l0 - 1) * 1024];
    }

    #pragma unroll 2
    for (int t = 0; t < CHL; ++t) {
        const int l = l0 + t;
        const long bl = (long)b * LSEQ + l;
        float xw3 = xz[rowbase + (long)l * 1024];
        float ua = cbe + cw4[0] * xw0 + cw4[1] * xw1 + cw4[2] * xw2 + cw4[3] * xw3;
        float u  = ua / (1.f + __expf(-ua));
        xw0 = xw1; xw1 = xw2; xw2 = xw3;

        const float* dr = dbl + bl * 80;
        float raw = dtbe;
        #pragma unroll
        for (int qd = 0; qd < 4; ++qd) {
            float4 d4 = *(const float4*)(dr + qd * 4);
            raw += wt[qd * 4 + 0] * d4.x + wt[qd * 4 + 1] * d4.y
                 + wt[qd * 4 + 2] * d4.z + wt[qd * 4 + 3] * d4.w;
        }
        float dt = (raw > 20.f) ? raw : log1pf(__expf(raw));
        float xx = dt * u;

        float y = 0.f;
        const float* bp = dr + 16;
        const float* cp = dr + 48;
        #pragma unroll
        for (int qd = 0; qd < 8; ++qd) {
            float4 b4 = *(const float4*)(bp + qd * 4);
            float4 c4 = *(const float4*)(cp + qd * 4);
            #pragma unroll
            for (int j = 0; j < 4; ++j) {
                const int n = qd * 4 + j;
                float bn = (j == 0) ? b4.x : (j == 1) ? b4.y : (j == 2) ? b4.z : b4.w;
                float cn = (j == 0) ? c4.x : (j == 1) ? c4.y : (j == 2) ? c4.z : c4.w;
                float dA = __expf(dt * Aen[n]);
                h[n] = fmaf(dA, h[n], xx * bn);
                y = fmaf(h[n], cn, y);
            }
        }
        y += u * dpe;
        float z = xz[rowbase + (long)l * 1024 + ESZ];
        float gz = z / (1.f + __expf(-z));
        yg[bl * ESZ + e] = __float2bfloat16(y * gz);
    }
}

// ---------------------------------------------------------------------------
extern "C" void kernel_launch(void* const* d_in, const int* in_sizes, int n_in,
                              void* d_out, int out_size, void* d_ws, size_t ws_size,
                              hipStream_t stream)
{
    const float* x    = (const float*)d_in[0];
    const float* n1g  = (const float*)d_in[1];
    const float* n1b  = (const float*)d_in[2];
    const float* cw   = (const float*)d_in[3];
    const float* cb   = (const float*)d_in[4];
    const float* ipw  = (const float*)d_in[5];
    const float* scw  = (const float*)d_in[6];
    const float* scb  = (const float*)d_in[7];
    const float* xpw  = (const float*)d_in[8];
    const float* dtw  = (const float*)d_in[9];
    const float* dtbi = (const float*)d_in[10];
    const float* alog = (const float*)d_in[11];
    const float* dp   = (const float*)d_in[12];
    const float* opw  = (const float*)d_in[13];
    const float* n2g  = (const float*)d_in[14];
    const float* n2b  = (const float*)d_in[15];
    const float* w1   = (const float*)d_in[16];
    const float* b1   = (const float*)d_in[17];
    const float* w2   = (const float*)d_in[18];
    const float* b2   = (const float*)d_in[19];
    float* out = (float*)d_out;

    // Workspace layout (float units) — fully disjoint, ~78.7 MB total.
    float* ws = (float*)d_ws;
    __hip_bfloat16* hmb  = (__hip_bfloat16*)(ws + 0);         //   524,288 f
    float*          xz   = ws + 524288;                       // 4,194,304 f
    __hip_bfloat16* ub   = (__hip_bfloat16*)(ws + 4718592);   // 1,048,576 f
    float*          dbl  = ws + 5767168;                      //   327,680 f
    float*          P    = ws + 6094848;                      // 4,194,304 f
    float*          Q    = ws + 10289152;                     // 4,194,304 f
    __hip_bfloat16* ygb  = (__hip_bfloat16*)(ws + 14483456);  // 1,048,576 f
    float*          hres = ws + 15532032;                     // 1,048,576 f
    __hip_bfloat16* h1b  = (__hip_bfloat16*)(ws + 16580608);  //   524,288 f
    __hip_bfloat16* midb = (__hip_bfloat16*)(ws + 17104896);  // 2,097,152 f
    __hip_bfloat16* wb   = (__hip_bfloat16*)(ws + 19202048);  //   479,232 f (all bf16 weights)
    __hip_bfloat16* ipwb = wb;                                // 262,144 e
    __hip_bfloat16* opwb = wb + 262144;                       // 131,072 e
    __hip_bfloat16* w1b  = wb + 393216;                       // 262,144 e
    __hip_bfloat16* w2b  = wb + 655360;                       // 262,144 e
    __hip_bfloat16* xpwb = wb + 917504;                       //  40,960 e

    // 1. all weight conversions (one kernel)
    convert_weights<<<936, 256, 0, stream>>>(ipw, opw, w1, w2, xpw, wb);
    // 2. fused LN1 + conv3 + residual -> bf16 hm
    ln1_conv3_kernel<<<MROWS, 256, 0, stream>>>(x, n1g, n1b, cw, cb, hmb);
    // 3. in_proj (MFMA): xz = hm @ ipw^T  [4096,1024,256]
    gemm_mfma<128, 128, EPI_NONE, 0><<<dim3(32, 8), 256, 0, stream>>>(
        hmb, 256, ipwb, 256, xz, 1024, 256, nullptr, nullptr, 0);
    // 4. causal conv4 + silu -> bf16 ub
    conv4_silu_kernel<<<8192, 256, 0, stream>>>(xz, scw, scb, ub);
    // 5. x_proj (MFMA): dbl = ub @ xpw^T  [4096,80,512]
    xproj_mfma<<<64, 256, 0, stream>>>(ub, xpwb, dbl);
    // 6-8. chunked selective scan (u, dt recomputed in-kernel) -> bf16 yg
    scan_s1<<<512, 256, 0, stream>>>(xz, dbl, alog, dtw, dtbi, scw, scb, P, Q);
    scan_s2<<<256, 256, 0, stream>>>(P, Q);
    scan_s3<<<512, 256, 0, stream>>>(xz, dbl, alog, dtw, dtbi, scw, scb, dp, P, ygb);
    // 9. out_proj (MFMA) + residual: hres = yg @ opw^T + x
    gemm_mfma<64, 128, EPI_RES, 0><<<dim3(64, 2), 256, 0, stream>>>(
        ygb, 512, opwb, 512, hres, 256, 512, nullptr, x, 256);
    // 10. LN2 -> bf16
    ln_kernel<<<MROWS, 256, 0, stream>>>(hres, n2g, n2b, h1b);
    // 11. MLP1 (MFMA) + gelu -> bf16 mid
    gemm_mfma<128, 128, EPI_GELU, 1><<<dim3(32, 8), 256, 0, stream>>>(
        h1b, 256, w1b, 256, midb, 1024, 256, b1, nullptr, 0);
    // 12. MLP2 (MFMA) + bias + residual: out = mid @ w2^T + b2 + hres
    gemm_mfma<64, 128, EPI_BIAS_RES, 0><<<dim3(64, 2), 256, 0, stream>>>(
        midb, 1024, w2b, 1024, out, 256, 1024, b2, hres, 256);
}

// Round 5
// 279.428 us; speedup vs baseline: 3.8504x; 1.1236x over previous
//
#include <hip/hip_runtime.h>
#include <hip/hip_bf16.h>
#include <math.h>

// Problem constants
#define BATCH 4
#define LSEQ  1024
#define DIM   256
#define ESZ   512      // E = 2*DIM
#define NST   32       // D_STATE
#define RNK   16       // DT_RANK
#define MROWS 4096     // B*L
#define NCH   64       // scan chunks
#define CHL   16       // chunk length (NCH*CHL == LSEQ)

typedef __attribute__((ext_vector_type(8))) short bf16x8;
typedef __attribute__((ext_vector_type(4))) float f32x4;

// ---------------------------------------------------------------------------
// All weight fp32->bf16 conversions in ONE kernel.
// Segments (float4 units): ipw 65536 | opw 32768 | w1 65536 | w2 65536 | xpw 10240
// ---------------------------------------------------------------------------
__global__ __launch_bounds__(256) void convert_weights(
    const float* __restrict__ ipw, const float* __restrict__ opw,
    const float* __restrict__ w1,  const float* __restrict__ w2,
    const float* __restrict__ xpw, __hip_bfloat16* __restrict__ dst)
{
    int i = blockIdx.x * 256 + threadIdx.x;   // over 239616 float4s
    if (i >= 239616) return;
    const float* s; int off;
    if      (i < 65536)  { s = ipw; off = i; }
    else if (i < 98304)  { s = opw; off = i - 65536; }
    else if (i < 163840) { s = w1;  off = i - 98304; }
    else if (i < 229376) { s = w2;  off = i - 163840; }
    else                 { s = xpw; off = i - 229376; }
    float4 v = ((const float4*)s)[off];
    union { __hip_bfloat16 h[4]; short4 s4; } u;
    u.h[0] = __float2bfloat16(v.x);
    u.h[1] = __float2bfloat16(v.y);
    u.h[2] = __float2bfloat16(v.z);
    u.h[3] = __float2bfloat16(v.w);
    ((short4*)dst)[i] = u.s4;
}

// ---------------------------------------------------------------------------
// Fused LN1 + dwconv3 + residual -> bf16 (halo LN recomputed in-block).
// ---------------------------------------------------------------------------
__global__ __launch_bounds__(256) void ln1_conv3_kernel(
    const float* __restrict__ x, const float* __restrict__ g,
    const float* __restrict__ b, const float* __restrict__ cw,
    const float* __restrict__ cb, __hip_bfloat16* __restrict__ hm)
{
    const int row = blockIdx.x;
    const int l   = row & (LSEQ - 1);
    const int d   = threadIdx.x;
    const float gc = g[d], bc = b[d];

    float xc = x[row * DIM + d];
    float xl = (l > 0)        ? x[(row - 1) * DIM + d] : 0.f;
    float xr = (l < LSEQ - 1) ? x[(row + 1) * DIM + d] : 0.f;

    float a[6] = { xc, xc * xc, xl, xl * xl, xr, xr * xr };
    #pragma unroll
    for (int o = 32; o > 0; o >>= 1)
        #pragma unroll
        for (int j = 0; j < 6; ++j) a[j] += __shfl_down(a[j], o, 64);
    __shared__ float red[4][6];
    if ((d & 63) == 0)
        #pragma unroll
        for (int j = 0; j < 6; ++j) red[d >> 6][j] = a[j];
    __syncthreads();
    float t[6];
    #pragma unroll
    for (int j = 0; j < 6; ++j)
        t[j] = red[0][j] + red[1][j] + red[2][j] + red[3][j];

    auto ln = [&](float v, float s, float s2) {
        float m  = s * (1.f / DIM);
        float vr = s2 * (1.f / DIM) - m * m;
        return (v - m) * rsqrtf(vr + 1e-5f) * gc + bc;
    };
    float ln_c = ln(xc, t[0], t[1]);
    float acc  = cw[d * 3 + 1] * ln_c + cb[d] + ln_c;
    if (l > 0)        acc += cw[d * 3 + 0] * ln(xl, t[2], t[3]);
    if (l < LSEQ - 1) acc += cw[d * 3 + 2] * ln(xr, t[4], t[5]);
    hm[row * DIM + d] = __float2bfloat16(acc);
}

// ---------------------------------------------------------------------------
// Plain LayerNorm (LN2) -> bf16
// ---------------------------------------------------------------------------
__global__ __launch_bounds__(256) void ln_kernel(
    const float* __restrict__ x, const float* __restrict__ g,
    const float* __restrict__ b, __hip_bfloat16* __restrict__ y)
{
    const int row = blockIdx.x;
    const int tid = threadIdx.x;
    float v = x[row * DIM + tid];
    float s = v, s2 = v * v;
    #pragma unroll
    for (int o = 32; o > 0; o >>= 1) {
        s  += __shfl_down(s,  o, 64);
        s2 += __shfl_down(s2, o, 64);
    }
    __shared__ float ls[4], ls2[4];
    if ((tid & 63) == 0) { ls[tid >> 6] = s; ls2[tid >> 6] = s2; }
    __syncthreads();
    float ts  = ls[0]  + ls[1]  + ls[2]  + ls[3];
    float ts2 = ls2[0] + ls2[1] + ls2[2] + ls2[3];
    float mean = ts * (1.f / DIM);
    float var  = ts2 * (1.f / DIM) - mean * mean;
    float inv  = rsqrtf(var + 1e-5f);
    y[row * DIM + tid] =
        __float2bfloat16((v - mean) * inv * g[tid] + b[tid]);
}

// ---------------------------------------------------------------------------
// causal dwconv4 + SiLU -> bf16 ub (for x_proj; scans recompute fp32 u).
// ---------------------------------------------------------------------------
__global__ __launch_bounds__(256) void conv4_silu_kernel(
    const float* __restrict__ xz, const float* __restrict__ w,
    const float* __restrict__ cb, __hip_bfloat16* __restrict__ ub)
{
    const int i  = blockIdx.x * 256 + threadIdx.x;   // over 4096*512
    const int e  = i & (ESZ - 1);
    const int bl = i >> 9;
    const int l  = bl & (LSEQ - 1);
    float acc = cb[e];
    #pragma unroll
    for (int k = 0; k < 4; ++k) {
        int ls = l + k - 3;
        if (ls >= 0) acc += w[e * 4 + k] * xz[(long)(bl + k - 3) * 1024 + e];
    }
    float sv = acc / (1.f + __expf(-acc));
    ub[(long)bl * ESZ + e] = __float2bfloat16(sv);
}

// ---------------------------------------------------------------------------
// dt precompute: dtf[row,e] = softplus(dtb[e] + dbl[row,:16] . dtw[e,:])
// One block per row; dbl row staged in LDS.
// ---------------------------------------------------------------------------
__global__ __launch_bounds__(256) void dt_kernel(
    const float* __restrict__ dbl, const float* __restrict__ dtw,
    const float* __restrict__ dtb, float* __restrict__ dtf)
{
    const int row = blockIdx.x;
    __shared__ float dr[RNK];
    if (threadIdx.x < RNK) dr[threadIdx.x] = dbl[(long)row * 80 + threadIdx.x];
    __syncthreads();
    #pragma unroll
    for (int hh = 0; hh < 2; ++hh) {
        const int e = threadIdx.x + hh * 256;
        float raw = dtb[e];
        #pragma unroll
        for (int qd = 0; qd < 4; ++qd) {
            float4 w4 = *(const float4*)(dtw + e * RNK + qd * 4);
            raw += w4.x * dr[qd * 4 + 0] + w4.y * dr[qd * 4 + 1]
                 + w4.z * dr[qd * 4 + 2] + w4.w * dr[qd * 4 + 3];
        }
        dtf[(long)row * ESZ + e] = (raw > 20.f) ? raw : log1pf(__expf(raw));
    }
}

// ---------------------------------------------------------------------------
// Epilogue ids
// ---------------------------------------------------------------------------
#define EPI_NONE      0
#define EPI_GELU      2
#define EPI_RES       3
#define EPI_BIAS_RES  4

// ---------------------------------------------------------------------------
// bf16 MFMA GEMM with global->reg prefetch pipeline.
// C[M,N] = A[M,K] @ W[N,K]^T (+ epilogue). 256 thr = 4 waves.
// BM=64 (waves split N), BN in {64,128}.
// ---------------------------------------------------------------------------
template <int BM, int BN, int EPI, int OUT_BF16>
__global__ __launch_bounds__(256) void gemm_mfma(
    const __hip_bfloat16* __restrict__ A, int lda,
    const __hip_bfloat16* __restrict__ W, int ldw,
    void* __restrict__ Cout, int ldc, int K,
    const float* __restrict__ bias,
    const float* __restrict__ res, int ldres)
{
    constexpr int BK = 64;
    constexpr int LS = BK + 8;
    constexpr int WAVES_M = BM / 64;          // 1
    constexpr int WAVES_N = 4 / WAVES_M;      // 4
    constexpr int WTN = BN / WAVES_N;         // 16 or 32
    constexpr int AMF = 4;
    constexpr int BNF = WTN / 16;
    constexpr int AR = BM / 32;
    constexpr int BR = BN / 32;

    __shared__ __hip_bfloat16 As[BM * LS];
    __shared__ __hip_bfloat16 Ws[BN * LS];

    const int tid  = threadIdx.x;
    const int lane = tid & 63;
    const int wave = tid >> 6;
    const int wm   = (wave / WAVES_N) * 64;
    const int wn   = (wave % WAVES_N) * WTN;
    const int m0   = blockIdx.x * BM;
    const int n0   = blockIdx.y * BN;
    const int srow = tid >> 3;
    const int scol = (tid & 7) * 8;
    const int q    = lane >> 4;
    const int lr   = lane & 15;

    f32x4 acc[AMF][BNF];
    #pragma unroll
    for (int i = 0; i < AMF; ++i)
        #pragma unroll
        for (int j = 0; j < BNF; ++j)
            acc[i][j] = (f32x4){0.f, 0.f, 0.f, 0.f};

    const __hip_bfloat16* Ab = A + (long)m0 * lda;
    const __hip_bfloat16* Wb = W + (long)n0 * ldw;

    float4 ar[AR], wr[BR];
    #pragma unroll
    for (int r = 0; r < AR; ++r)
        ar[r] = *(const float4*)(Ab + (long)(r * 32 + srow) * lda + scol);
    #pragma unroll
    for (int r = 0; r < BR; ++r)
        wr[r] = *(const float4*)(Wb + (long)(r * 32 + srow) * ldw + scol);

    for (int k0 = 0; k0 < K; k0 += BK) {
        __syncthreads();
        #pragma unroll
        for (int r = 0; r < AR; ++r)
            *(float4*)(&As[(r * 32 + srow) * LS + scol]) = ar[r];
        #pragma unroll
        for (int r = 0; r < BR; ++r)
            *(float4*)(&Ws[(r * 32 + srow) * LS + scol]) = wr[r];
        __syncthreads();
        if (k0 + BK < K) {   // prefetch next K-tile while MFMAs run
            #pragma unroll
            for (int r = 0; r < AR; ++r)
                ar[r] = *(const float4*)(Ab + (long)(r * 32 + srow) * lda + k0 + BK + scol);
            #pragma unroll
            for (int r = 0; r < BR; ++r)
                wr[r] = *(const float4*)(Wb + (long)(r * 32 + srow) * ldw + k0 + BK + scol);
        }
        #pragma unroll
        for (int ks = 0; ks < 2; ++ks) {
            bf16x8 af[AMF], bfr[BNF];
            #pragma unroll
            for (int i = 0; i < AMF; ++i)
                af[i] = *(const bf16x8*)(&As[(wm + i * 16 + lr) * LS + ks * 32 + q * 8]);
            #pragma unroll
            for (int j = 0; j < BNF; ++j)
                bfr[j] = *(const bf16x8*)(&Ws[(wn + j * 16 + lr) * LS + ks * 32 + q * 8]);
            #pragma unroll
            for (int i = 0; i < AMF; ++i)
                #pragma unroll
                for (int j = 0; j < BNF; ++j)
                    acc[i][j] = __builtin_amdgcn_mfma_f32_16x16x32_bf16(
                        af[i], bfr[j], acc[i][j], 0, 0, 0);
        }
    }

    #pragma unroll
    for (int i = 0; i < AMF; ++i) {
        #pragma unroll
        for (int j = 0; j < BNF; ++j) {
            const int col  = n0 + wn + j * 16 + lr;
            const int rowb = m0 + wm + i * 16 + q * 4;
            #pragma unroll
            for (int r = 0; r < 4; ++r) {
                const int row = rowb + r;
                float v = acc[i][j][r];
                if (EPI == EPI_GELU) {
                    v += bias[col];
                    v = 0.5f * v * (1.f + erff(v * 0.70710678118654752f));
                } else if (EPI == EPI_RES) {
                    v += res[(long)row * ldres + col];
                } else if (EPI == EPI_BIAS_RES) {
                    v += bias[col] + res[(long)row * ldres + col];
                }
                if (OUT_BF16)
                    ((__hip_bfloat16*)Cout)[(long)row * ldc + col] = __float2bfloat16(v);
                else
                    ((float*)Cout)[(long)row * ldc + col] = v;
            }
        }
    }
}

// ---------------------------------------------------------------------------
// x_proj MFMA: dbl[4096,80] = ub[4096,512] @ xpwb[80,512]^T, with prefetch.
// ---------------------------------------------------------------------------
__global__ __launch_bounds__(256) void xproj_mfma(
    const __hip_bfloat16* __restrict__ A,
    const __hip_bfloat16* __restrict__ W,
    float* __restrict__ C)
{
    constexpr int LS = 72;
    __shared__ __hip_bfloat16 As[64 * LS];
    __shared__ __hip_bfloat16 Ws[80 * LS];
    const int tid  = threadIdx.x;
    const int lane = tid & 63;
    const int wave = tid >> 6;
    const int wm   = wave * 16;
    const int m0   = blockIdx.x * 64;
    const int srow = tid >> 3;
    const int scol = (tid & 7) * 8;
    const int q    = lane >> 4;
    const int lr   = lane & 15;

    f32x4 acc[5];
    #pragma unroll
    for (int j = 0; j < 5; ++j) acc[j] = (f32x4){0.f, 0.f, 0.f, 0.f};

    float4 ar[2], wr[3];
    #pragma unroll
    for (int r = 0; r < 2; ++r)
        ar[r] = *(const float4*)(A + (long)(m0 + r * 32 + srow) * 512 + scol);
    #pragma unroll
    for (int r = 0; r < 3; ++r) {
        int row = r * 32 + srow;
        wr[r] = (row < 80) ? *(const float4*)(W + (long)row * 512 + scol)
                           : make_float4(0.f, 0.f, 0.f, 0.f);
    }

    for (int k0 = 0; k0 < 512; k0 += 64) {
        __syncthreads();
        #pragma unroll
        for (int r = 0; r < 2; ++r)
            *(float4*)(&As[(r * 32 + srow) * LS + scol]) = ar[r];
        #pragma unroll
        for (int r = 0; r < 3; ++r) {
            int row = r * 32 + srow;
            if (row < 80) *(float4*)(&Ws[row * LS + scol]) = wr[r];
        }
        __syncthreads();
        if (k0 + 64 < 512) {
            #pragma unroll
            for (int r = 0; r < 2; ++r)
                ar[r] = *(const float4*)(A + (long)(m0 + r * 32 + srow) * 512 + k0 + 64 + scol);
            #pragma unroll
            for (int r = 0; r < 3; ++r) {
                int row = r * 32 + srow;
                if (row < 80)
                    wr[r] = *(const float4*)(W + (long)row * 512 + k0 + 64 + scol);
            }
        }
        #pragma unroll
        for (int ks = 0; ks < 2; ++ks) {
            bf16x8 af = *(const bf16x8*)(&As[(wm + lr) * LS + ks * 32 + q * 8]);
            #pragma unroll
            for (int j = 0; j < 5; ++j) {
                bf16x8 bf = *(const bf16x8*)(&Ws[(j * 16 + lr) * LS + ks * 32 + q * 8]);
                acc[j] = __builtin_amdgcn_mfma_f32_16x16x32_bf16(af, bf, acc[j], 0, 0, 0);
            }
        }
    }
    #pragma unroll
    for (int j = 0; j < 5; ++j)
        #pragma unroll
        for (int r = 0; r < 4; ++r)
            C[(long)(m0 + wm + q * 4 + r) * 80 + j * 16 + lr] = acc[j][r];
}

// ---------------------------------------------------------------------------
// Chunked parallel selective scan, layout B (lane owns channel e, 32 states
// in regs). B/C rows staged in LDS per chunk (broadcast reads); dt from
// precomputed dtf; u recomputed fp32-exact from xz (rolling 4-tap).
// Grid: B * NCH * (E/256) = 512 blocks. P/Q layout: [b][c][n][e].
// ---------------------------------------------------------------------------
__global__ __launch_bounds__(256) void scan_s1(
    const float* __restrict__ xz, const float* __restrict__ dbl,
    const float* __restrict__ dtf, const float* __restrict__ A_log,
    const float* __restrict__ scw, const float* __restrict__ scb,
    float* __restrict__ P, float* __restrict__ Q)
{
    const int tid = threadIdx.x;
    const int e  = ((blockIdx.x & 1) << 8) + tid;
    const int bc = blockIdx.x >> 1;
    const int c  = bc & (NCH - 1);
    const int b  = bc >> 6;

    __shared__ float sBC[CHL][64];   // [t][0:32]=B, [32:64]=C
    {
        const int r  = tid >> 4;
        const int cg = (tid & 15) * 4;
        *(float4*)&sBC[r][cg] =
            *(const float4*)(dbl + ((long)b * LSEQ + c * CHL + r) * 80 + 16 + cg);
    }

    float Aen[NST];
    #pragma unroll
    for (int qd = 0; qd < 8; ++qd) {
        float4 a4 = *(const float4*)(A_log + e * NST + qd * 4);
        Aen[qd * 4 + 0] = -__expf(a4.x);
        Aen[qd * 4 + 1] = -__expf(a4.y);
        Aen[qd * 4 + 2] = -__expf(a4.z);
        Aen[qd * 4 + 3] = -__expf(a4.w);
    }
    float cw4[4];
    #pragma unroll
    for (int k = 0; k < 4; ++k) cw4[k] = scw[e * 4 + k];
    const float cbe = scb[e];

    const int l0 = c * CHL;
    const long rowbase = ((long)b * LSEQ) * 1024 + e;
    float xw0, xw1, xw2;
    if (c == 0) { xw0 = xw1 = xw2 = 0.f; }
    else {
        xw0 = xz[rowbase + (long)(l0 - 3) * 1024];
        xw1 = xz[rowbase + (long)(l0 - 2) * 1024];
        xw2 = xz[rowbase + (long)(l0 - 1) * 1024];
    }

    float Pv[NST], Qv[NST];
    #pragma unroll
    for (int n = 0; n < NST; ++n) { Pv[n] = 1.f; Qv[n] = 0.f; }
    __syncthreads();

    for (int t = 0; t < CHL; ++t) {
        const int l = l0 + t;
        const long bl = (long)b * LSEQ + l;
        float xw3 = xz[rowbase + (long)l * 1024];
        float ua = cbe + cw4[0] * xw0 + cw4[1] * xw1 + cw4[2] * xw2 + cw4[3] * xw3;
        float u  = ua / (1.f + __expf(-ua));
        xw0 = xw1; xw1 = xw2; xw2 = xw3;

        float dt = dtf[bl * ESZ + e];
        float xx = dt * u;

        #pragma unroll
        for (int qd = 0; qd < 8; ++qd) {
            float4 b4 = *(const float4*)&sBC[t][qd * 4];
            #pragma unroll
            for (int j = 0; j < 4; ++j) {
                const int n = qd * 4 + j;
                float bn = (j == 0) ? b4.x : (j == 1) ? b4.y : (j == 2) ? b4.z : b4.w;
                float dA = __expf(dt * Aen[n]);
                Pv[n] *= dA;
                Qv[n] = fmaf(dA, Qv[n], xx * bn);
            }
        }
    }
    const long pb = ((long)(b * NCH + c) * NST) * ESZ + e;
    #pragma unroll
    for (int n = 0; n < NST; ++n) {
        P[pb + (long)n * ESZ] = Pv[n];
        Q[pb + (long)n * ESZ] = Qv[n];
    }
}

// Sequential combine over chunks; writes Hinit (chunk-entry state) over P.
__global__ __launch_bounds__(256) void scan_s2(
    float* __restrict__ P, const float* __restrict__ Q)
{
    const int tg = blockIdx.x * 256 + threadIdx.x;   // 65536 = B*NST*E
    const int e  = tg & (ESZ - 1);
    const int n  = (tg >> 9) & (NST - 1);
    const int b  = tg >> 14;
    float h = 0.f;
    #pragma unroll 4
    for (int c = 0; c < NCH; ++c) {
        const long idx = ((long)(b * NCH + c) * NST + n) * ESZ + e;
        float Pv = P[idx];
        float Qv = Q[idx];
        P[idx] = h;
        h = fmaf(Pv, h, Qv);
    }
}

__global__ __launch_bounds__(256) void scan_s3(
    const float* __restrict__ xz, const float* __restrict__ dbl,
    const float* __restrict__ dtf, const float* __restrict__ A_log,
    const float* __restrict__ scw, const float* __restrict__ scb,
    const float* __restrict__ Dp, const float* __restrict__ H,
    __hip_bfloat16* __restrict__ yg)
{
    const int tid = threadIdx.x;
    const int e  = ((blockIdx.x & 1) << 8) + tid;
    const int bc = blockIdx.x >> 1;
    const int c  = bc & (NCH - 1);
    const int b  = bc >> 6;

    __shared__ float sBC[CHL][64];
    {
        const int r  = tid >> 4;
        const int cg = (tid & 15) * 4;
        *(float4*)&sBC[r][cg] =
            *(const float4*)(dbl + ((long)b * LSEQ + c * CHL + r) * 80 + 16 + cg);
    }

    float Aen[NST];
    #pragma unroll
    for (int qd = 0; qd < 8; ++qd) {
        float4 a4 = *(const float4*)(A_log + e * NST + qd * 4);
        Aen[qd * 4 + 0] = -__expf(a4.x);
        Aen[qd * 4 + 1] = -__expf(a4.y);
        Aen[qd * 4 + 2] = -__expf(a4.z);
        Aen[qd * 4 + 3] = -__expf(a4.w);
    }
    float cw4[4];
    #pragma unroll
    for (int k = 0; k < 4; ++k) cw4[k] = scw[e * 4 + k];
    const float cbe = scb[e];
    const float dpe = Dp[e];

    float h[NST];
    const long pb = ((long)(b * NCH + c) * NST) * ESZ + e;
    #pragma unroll
    for (int n = 0; n < NST; ++n) h[n] = H[pb + (long)n * ESZ];

    const int l0 = c * CHL;
    const long rowbase = ((long)b * LSEQ) * 1024 + e;
    float xw0, xw1, xw2;
    if (c == 0) { xw0 = xw1 = xw2 = 0.f; }
    else {
        xw0 = xz[rowbase + (long)(l0 - 3) * 1024];
        xw1 = xz[rowbase + (long)(l0 - 2) * 1024];
        xw2 = xz[rowbase + (long)(l0 - 1) * 1024];
    }
    __syncthreads();

    for (int t = 0; t < CHL; ++t) {
        const int l = l0 + t;
        const long bl = (long)b * LSEQ + l;
        float xw3 = xz[rowbase + (long)l * 1024];
        float ua = cbe + cw4[0] * xw0 + cw4[1] * xw1 + cw4[2] * xw2 + cw4[3] * xw3;
        float u  = ua / (1.f + __expf(-ua));
        xw0 = xw1; xw1 = xw2; xw2 = xw3;

        float dt = dtf[bl * ESZ + e];
        float xx = dt * u;

        float y = 0.f;
        #pragma unroll
        for (int qd = 0; qd < 8; ++qd) {
            float4 b4 = *(const float4*)&sBC[t][qd * 4];
            float4 c4 = *(const float4*)&sBC[t][32 + qd * 4];
            #pragma unroll
            for (int j = 0; j < 4; ++j) {
                const int n = qd * 4 + j;
                float bn = (j == 0) ? b4.x : (j == 1) ? b4.y : (j == 2) ? b4.z : b4.w;
                float cn = (j == 0) ? c4.x : (j == 1) ? c4.y : (j == 2) ? c4.z : c4.w;
                float dA = __expf(dt * Aen[n]);
                h[n] = fmaf(dA, h[n], xx * bn);
                y = fmaf(h[n], cn, y);
            }
        }
        y += u * dpe;
        float z = xz[rowbase + (long)l * 1024 + ESZ];
        float gz = z / (1.f + __expf(-z));
        yg[bl * ESZ + e] = __float2bfloat16(y * gz);
    }
}

// ---------------------------------------------------------------------------
extern "C" void kernel_launch(void* const* d_in, const int* in_sizes, int n_in,
                              void* d_out, int out_size, void* d_ws, size_t ws_size,
                              hipStream_t stream)
{
    const float* x    = (const float*)d_in[0];
    const float* n1g  = (const float*)d_in[1];
    const float* n1b  = (const float*)d_in[2];
    const float* cw   = (const float*)d_in[3];
    const float* cb   = (const float*)d_in[4];
    const float* ipw  = (const float*)d_in[5];
    const float* scw  = (const float*)d_in[6];
    const float* scb  = (const float*)d_in[7];
    const float* xpw  = (const float*)d_in[8];
    const float* dtw  = (const float*)d_in[9];
    const float* dtbi = (const float*)d_in[10];
    const float* alog = (const float*)d_in[11];
    const float* dp   = (const float*)d_in[12];
    const float* opw  = (const float*)d_in[13];
    const float* n2g  = (const float*)d_in[14];
    const float* n2b  = (const float*)d_in[15];
    const float* w1   = (const float*)d_in[16];
    const float* b1   = (const float*)d_in[17];
    const float* w2   = (const float*)d_in[18];
    const float* b2   = (const float*)d_in[19];
    float* out = (float*)d_out;

    // Workspace layout (float units) — fully disjoint, ~87 MB total.
    float* ws = (float*)d_ws;
    __hip_bfloat16* hmb  = (__hip_bfloat16*)(ws + 0);         //   524,288 f
    float*          xz   = ws + 524288;                       // 4,194,304 f
    __hip_bfloat16* ub   = (__hip_bfloat16*)(ws + 4718592);   // 1,048,576 f
    float*          dbl  = ws + 5767168;                      //   327,680 f
    float*          dtf  = ws + 6094848;                      // 2,097,152 f
    float*          P    = ws + 8192000;                      // 4,194,304 f
    float*          Q    = ws + 12386304;                     // 4,194,304 f
    __hip_bfloat16* ygb  = (__hip_bfloat16*)(ws + 16580608);  // 1,048,576 f
    float*          hres = ws + 17629184;                     // 1,048,576 f
    __hip_bfloat16* h1b  = (__hip_bfloat16*)(ws + 18677760);  //   524,288 f
    __hip_bfloat16* midb = (__hip_bfloat16*)(ws + 19202048);  // 2,097,152 f
    __hip_bfloat16* wb   = (__hip_bfloat16*)(ws + 21299200);  //   479,232 f
    __hip_bfloat16* ipwb = wb;
    __hip_bfloat16* opwb = wb + 262144;
    __hip_bfloat16* w1b  = wb + 393216;
    __hip_bfloat16* w2b  = wb + 655360;
    __hip_bfloat16* xpwb = wb + 917504;

    // 1. all weight conversions
    convert_weights<<<936, 256, 0, stream>>>(ipw, opw, w1, w2, xpw, wb);
    // 2. fused LN1 + conv3 + residual -> bf16 hm
    ln1_conv3_kernel<<<MROWS, 256, 0, stream>>>(x, n1g, n1b, cw, cb, hmb);
    // 3. in_proj (MFMA): xz = hm @ ipw^T  [4096,1024,256]
    gemm_mfma<64, 128, EPI_NONE, 0><<<dim3(64, 8), 256, 0, stream>>>(
        hmb, 256, ipwb, 256, xz, 1024, 256, nullptr, nullptr, 0);
    // 4. causal conv4 + silu -> bf16 ub
    conv4_silu_kernel<<<8192, 256, 0, stream>>>(xz, scw, scb, ub);
    // 5. x_proj (MFMA): dbl = ub @ xpw^T  [4096,80,512]
    xproj_mfma<<<64, 256, 0, stream>>>(ub, xpwb, dbl);
    // 6. dt precompute
    dt_kernel<<<MROWS, 256, 0, stream>>>(dbl, dtw, dtbi, dtf);
    // 7-9. chunked selective scan -> bf16 yg
    scan_s1<<<512, 256, 0, stream>>>(xz, dbl, dtf, alog, scw, scb, P, Q);
    scan_s2<<<256, 256, 0, stream>>>(P, Q);
    scan_s3<<<512, 256, 0, stream>>>(xz, dbl, dtf, alog, scw, scb, dp, P, ygb);
    // 10. out_proj (MFMA) + residual: hres = yg @ opw^T + x
    gemm_mfma<64, 64, EPI_RES, 0><<<dim3(64, 4), 256, 0, stream>>>(
        ygb, 512, opwb, 512, hres, 256, 512, nullptr, x, 256);
    // 11. LN2 -> bf16
    ln_kernel<<<MROWS, 256, 0, stream>>>(hres, n2g, n2b, h1b);
    // 12. MLP1 (MFMA) + gelu -> bf16 mid
    gemm_mfma<64, 128, EPI_GELU, 1><<<dim3(64, 8), 256, 0, stream>>>(
        h1b, 256, w1b, 256, midb, 1024, 256, b1, nullptr, 0);
    // 13. MLP2 (MFMA) + bias + residual: out = mid @ w2^T + b2 + hres
    gemm_mfma<64, 64, EPI_BIAS_RES, 0><<<dim3(64, 4), 256, 0, stream>>>(
        midb, 1024, w2b, 1024, out, 256, 1024, b2, hres, 256);
}